// Round 1
// baseline (532.816 us; speedup 1.0000x reference)
//
#include <hip/hip_runtime.h>
#include <cstdint>

#define TDIM 1024
#define BDIM 4
#define MDIM 512
#define HDIM 8
#define KD   64
#define VD   64
#define EPSF 1e-6f

// workspace float offsets
#define OFF_QF   0u
#define OFF_KF   2097152u
#define OFF_VG   4194304u
#define OFF_NU   6291456u   // normalized numerator [B,T,H*V]
#define OFF_DEN  8388608u   // [B*H, T]
#define OFF_KSUM 8421376u   // [B*H,16,64]  (becomes exclusive prefix in-place)
#define OFF_KV   8454144u   // [B*H,16,64,64] (becomes exclusive prefix in-place)
// total 10,551,296 floats = 42.2 MB

__device__ __forceinline__ float phi_f(float x)  { return x > 0.f ? x + 1.f : __expf(x); }
__device__ __forceinline__ float sigm_f(float x) { return 1.f / (1.f + __expf(-x)); }
__device__ __forceinline__ float dot4(float4 a, float4 b) {
    return a.x * b.x + a.y * b.y + a.z * b.z + a.w * b.w;
}
#define FMA4(ACC, S, V) do { (ACC).x += (S)*(V).x; (ACC).y += (S)*(V).y; \
                             (ACC).z += (S)*(V).z; (ACC).w += (S)*(V).w; } while (0)

// ---------------------------------------------------------------------------
// Tiled fp32 GEMM: out[4096,512] = A[4096,512] @ W0[512,512]  (+epilogue)
// MODE 0: phi(x)   MODE 1: plain   MODE 2: dual -> (A@W0) * 2*sigmoid(A@W1+bias)
// tile 128x64, 256 threads, 8x4 per thread
// ---------------------------------------------------------------------------
template <int MODE>
__global__ __launch_bounds__(256) void gemm_k(const float* __restrict__ A,
                                              const float* __restrict__ W0,
                                              const float* __restrict__ W1,
                                              const float* __restrict__ bias,
                                              float* __restrict__ out) {
    __shared__ __align__(16) float AsT[16][132];
    __shared__ __align__(16) float Bs[16][68];
    __shared__ __align__(16) float Bs2[16][68];
    const int tid  = threadIdx.x;
    const int row0 = blockIdx.x * 128;
    const int n0   = blockIdx.y * 64;
    const int tm0  = (tid >> 4) * 8;
    const int tn0  = (tid & 15) * 4;
    const int ar   = tid >> 1, akq = tid & 1;
    const int br   = tid >> 4, bc4 = (tid & 15) * 4;

    float4 acc[8], acc2[8];
#pragma unroll
    for (int i = 0; i < 8; i++) {
        acc[i] = make_float4(0.f, 0.f, 0.f, 0.f);
        acc2[i] = make_float4(0.f, 0.f, 0.f, 0.f);
    }

    for (int kt = 0; kt < 512; kt += 16) {
        const float* ap = A + (size_t)(row0 + ar) * 512 + kt + akq * 8;
        float4 a0 = *(const float4*)ap;
        float4 a1 = *(const float4*)(ap + 4);
        AsT[akq * 8 + 0][ar] = a0.x; AsT[akq * 8 + 1][ar] = a0.y;
        AsT[akq * 8 + 2][ar] = a0.z; AsT[akq * 8 + 3][ar] = a0.w;
        AsT[akq * 8 + 4][ar] = a1.x; AsT[akq * 8 + 5][ar] = a1.y;
        AsT[akq * 8 + 6][ar] = a1.z; AsT[akq * 8 + 7][ar] = a1.w;
        *(float4*)&Bs[br][bc4] = *(const float4*)(W0 + (size_t)(kt + br) * 512 + n0 + bc4);
        if (MODE == 2)
            *(float4*)&Bs2[br][bc4] = *(const float4*)(W1 + (size_t)(kt + br) * 512 + n0 + bc4);
        __syncthreads();
#pragma unroll
        for (int kk = 0; kk < 16; kk++) {
            float4 aL = *(const float4*)&AsT[kk][tm0];
            float4 aH = *(const float4*)&AsT[kk][tm0 + 4];
            float4 b  = *(const float4*)&Bs[kk][tn0];
            float av[8] = {aL.x, aL.y, aL.z, aL.w, aH.x, aH.y, aH.z, aH.w};
#pragma unroll
            for (int i = 0; i < 8; i++) FMA4(acc[i], av[i], b);
            if (MODE == 2) {
                float4 b2 = *(const float4*)&Bs2[kk][tn0];
#pragma unroll
                for (int i = 0; i < 8; i++) FMA4(acc2[i], av[i], b2);
            }
        }
        __syncthreads();
    }

    float4 bb = make_float4(0.f, 0.f, 0.f, 0.f);
    if (MODE == 2) bb = *(const float4*)(bias + n0 + tn0);
#pragma unroll
    for (int i = 0; i < 8; i++) {
        float4 r = acc[i];
        if (MODE == 0) {
            r.x = phi_f(r.x); r.y = phi_f(r.y); r.z = phi_f(r.z); r.w = phi_f(r.w);
        } else if (MODE == 2) {
            float4 g = acc2[i];
            r.x *= 2.f * sigm_f(g.x + bb.x);
            r.y *= 2.f * sigm_f(g.y + bb.y);
            r.z *= 2.f * sigm_f(g.z + bb.z);
            r.w *= 2.f * sigm_f(g.w + bb.w);
        }
        *(float4*)(out + (size_t)(row0 + tm0 + i) * 512 + n0 + tn0) = r;
    }
}

// ---------------------------------------------------------------------------
// K2a: per-(b,h,chunk) sums: kv[k][v] = sum_t kf[t][k]*vg[t][v]; ksum[k]
// ---------------------------------------------------------------------------
__global__ __launch_bounds__(256) void chunksum_k(const float* __restrict__ kf,
                                                  const float* __restrict__ vg,
                                                  float* __restrict__ kv,
                                                  float* __restrict__ ksum) {
    __shared__ __align__(16) float kf_c[64][68];
    __shared__ __align__(16) float vg_c[64][68];
    const int tid = threadIdx.x;
    const int bh = blockIdx.x, c = blockIdx.y;
    const int b = bh >> 3, h = bh & 7;
    const int r = tid >> 2, qq = tid & 3;
    const size_t rowbase = ((size_t)(b * TDIM + c * 64 + r)) * 512 + h * 64 + qq * 16;
#pragma unroll
    for (int u = 0; u < 4; u++) {
        *(float4*)&kf_c[r][qq * 16 + 4 * u] = *(const float4*)(kf + rowbase + 4 * u);
        *(float4*)&vg_c[r][qq * 16 + 4 * u] = *(const float4*)(vg + rowbase + 4 * u);
    }
    __syncthreads();
    const int k0 = (tid >> 4) * 4;
    const int v0 = (tid & 15) * 4;
    float4 a4[4];
#pragma unroll
    for (int i = 0; i < 4; i++) a4[i] = make_float4(0.f, 0.f, 0.f, 0.f);
    for (int t = 0; t < 64; t++) {
        float4 kk4 = *(const float4*)&kf_c[t][k0];
        float4 vv  = *(const float4*)&vg_c[t][v0];
        FMA4(a4[0], kk4.x, vv); FMA4(a4[1], kk4.y, vv);
        FMA4(a4[2], kk4.z, vv); FMA4(a4[3], kk4.w, vv);
    }
    const size_t base = (size_t)(bh * 16 + c) * 64;
#pragma unroll
    for (int i = 0; i < 4; i++)
        *(float4*)(kv + (base + k0 + i) * 64 + v0) = a4[i];
    if (tid < 64) {
        float s = 0.f;
        for (int t = 0; t < 64; t++) s += kf_c[t][tid];
        ksum[base + tid] = s;
    }
}

// ---------------------------------------------------------------------------
// K2b: in-place exclusive prefix over the 16 chunks (per bh)
// ---------------------------------------------------------------------------
__global__ __launch_bounds__(256) void prefix_k(float* __restrict__ kv,
                                                float* __restrict__ ksum) {
    const int tid = threadIdx.x;
    const int bh = blockIdx.x;
    float4 run[4];
#pragma unroll
    for (int u = 0; u < 4; u++) run[u] = make_float4(0.f, 0.f, 0.f, 0.f);
    const int d0 = tid * 16;
    for (int c = 0; c < 16; c++) {
        float* p = kv + (size_t)(bh * 16 + c) * 4096 + d0;
#pragma unroll
        for (int u = 0; u < 4; u++) {
            float4 x = *(float4*)(p + 4 * u);
            *(float4*)(p + 4 * u) = run[u];
            run[u].x += x.x; run[u].y += x.y; run[u].z += x.z; run[u].w += x.w;
        }
    }
    if (tid < 64) {
        float r2 = 0.f;
        for (int c = 0; c < 16; c++) {
            float* p = ksum + (size_t)(bh * 16 + c) * 64 + tid;
            float x = *p; *p = r2; r2 += x;
        }
    }
}

// ---------------------------------------------------------------------------
// K2c: per-(b,h,chunk): denom + normalized numerator
// ---------------------------------------------------------------------------
__global__ __launch_bounds__(256) void chunkout_k(const float* __restrict__ qf,
                                                  const float* __restrict__ kfp,
                                                  const float* __restrict__ vgp,
                                                  const float* __restrict__ kv,
                                                  const float* __restrict__ ksum,
                                                  float* __restrict__ numer,
                                                  float* __restrict__ denom) {
    __shared__ __align__(16) float qf_c[64][68];
    __shared__ __align__(16) float kf_c[64][68];
    __shared__ __align__(16) float vgT[64][68];
    __shared__ __align__(16) float kvT[64][68];
    __shared__ __align__(16) float sc[64][68];
    __shared__ __align__(16) float kpre_s[64];
    __shared__ __align__(16) float den_s[64];
    const int tid = threadIdx.x;
    const int bh = blockIdx.x, c = blockIdx.y;
    const int b = bh >> 3, h = bh & 7;
    const int r = tid >> 2, qq = tid & 3;
    {
        const size_t rowbase = ((size_t)(b * TDIM + c * 64 + r)) * 512 + h * 64 + qq * 16;
#pragma unroll
        for (int u = 0; u < 4; u++) {
            *(float4*)&qf_c[r][qq * 16 + 4 * u] = *(const float4*)(qf + rowbase + 4 * u);
            *(float4*)&kf_c[r][qq * 16 + 4 * u] = *(const float4*)(kfp + rowbase + 4 * u);
            float4 vv = *(const float4*)(vgp + rowbase + 4 * u);
            vgT[qq * 16 + 4 * u + 0][r] = vv.x; vgT[qq * 16 + 4 * u + 1][r] = vv.y;
            vgT[qq * 16 + 4 * u + 2][r] = vv.z; vgT[qq * 16 + 4 * u + 3][r] = vv.w;
        }
        const size_t kvbase = ((size_t)(bh * 16 + c) * 64 + r) * 64 + qq * 16;
#pragma unroll
        for (int u = 0; u < 4; u++) {
            float4 x = *(const float4*)(kv + kvbase + 4 * u);
            kvT[qq * 16 + 4 * u + 0][r] = x.x; kvT[qq * 16 + 4 * u + 1][r] = x.y;
            kvT[qq * 16 + 4 * u + 2][r] = x.z; kvT[qq * 16 + 4 * u + 3][r] = x.w;
        }
        if (tid < 64) kpre_s[tid] = ksum[(size_t)(bh * 16 + c) * 64 + tid];
    }
    __syncthreads();
    const int tt = tid >> 2, sq = tid & 3;
    float4 qreg[16];
#pragma unroll
    for (int u = 0; u < 16; u++) qreg[u] = *(const float4*)&qf_c[tt][4 * u];
    // phase A: intra-chunk causal scores
    for (int si = 0; si < 16; si++) {
        const int s = sq * 16 + si;
        float val = 0.f;
        if (s <= tt) {
#pragma unroll
            for (int u = 0; u < 16; u++)
                val += dot4(qreg[u], *(const float4*)&kf_c[s][4 * u]);
        }
        sc[tt][s] = val;
    }
    __syncthreads();
    float4 screg[16];
#pragma unroll
    for (int u = 0; u < 16; u++) screg[u] = *(const float4*)&sc[tt][4 * u];
    if (sq == 0) {
        float den = 0.f;
#pragma unroll
        for (int u = 0; u < 16; u++) {
            den += dot4(qreg[u], *(const float4*)&kpre_s[4 * u]);
            den += screg[u].x + screg[u].y + screg[u].z + screg[u].w;
        }
        den_s[tt] = den;
        denom[(size_t)bh * TDIM + c * 64 + tt] = den;
    }
    __syncthreads();
    const float inv = 1.f / (den_s[tt] + EPSF);
    for (int vi = 0; vi < 16; vi++) {
        const int v = sq * 16 + vi;
        float a = 0.f;
#pragma unroll
        for (int u = 0; u < 16; u++) {
            a += dot4(qreg[u], *(const float4*)&kvT[v][4 * u]);
            a += dot4(screg[u], *(const float4*)&vgT[v][4 * u]);
        }
        numer[((size_t)(b * TDIM + c * 64 + tt)) * 512 + h * 64 + v] = a * inv;
    }
}

// ---------------------------------------------------------------------------
// K3: att_map: scores recomputed as 64x64 tiles, normalized by denom, causal
// ---------------------------------------------------------------------------
__global__ __launch_bounds__(256) void attmap_k(const float* __restrict__ qf,
                                                const float* __restrict__ kfp,
                                                const float* __restrict__ denom,
                                                float* __restrict__ att) {
    __shared__ __align__(16) float qfT[64][68];
    __shared__ __align__(16) float kfT[64][68];
    __shared__ __align__(16) float inv_s[64];
    const int tid = threadIdx.x;
    const int bh = blockIdx.x;
    const int tt0 = blockIdx.y * 64;
    const int b = bh >> 3, h = bh & 7;
    const int r = tid >> 2, qq = tid & 3;
    {
        const size_t rowbase = ((size_t)(b * TDIM + tt0 + r)) * 512 + h * 64 + qq * 16;
#pragma unroll
        for (int u = 0; u < 4; u++) {
            float4 x = *(const float4*)(qf + rowbase + 4 * u);
            qfT[qq * 16 + 4 * u + 0][r] = x.x; qfT[qq * 16 + 4 * u + 1][r] = x.y;
            qfT[qq * 16 + 4 * u + 2][r] = x.z; qfT[qq * 16 + 4 * u + 3][r] = x.w;
        }
        if (tid < 64) inv_s[tid] = 1.f / (denom[(size_t)bh * TDIM + tt0 + tid] + EPSF);
    }
    __syncthreads();
    float* attb = att + (size_t)bh * TDIM * TDIM;
    const int tm0 = (tid >> 4) * 4;
    const int sn0 = (tid & 15) * 4;
    for (int st = 0; st < 16; st++) {
        const int s0 = st * 64;
        if (s0 <= tt0 + 63) {
            const size_t rb = ((size_t)(b * TDIM + s0 + r)) * 512 + h * 64 + qq * 16;
#pragma unroll
            for (int u = 0; u < 4; u++) {
                float4 x = *(const float4*)(kfp + rb + 4 * u);
                kfT[qq * 16 + 4 * u + 0][r] = x.x; kfT[qq * 16 + 4 * u + 1][r] = x.y;
                kfT[qq * 16 + 4 * u + 2][r] = x.z; kfT[qq * 16 + 4 * u + 3][r] = x.w;
            }
            __syncthreads();
            float4 acc4[4];
#pragma unroll
            for (int i = 0; i < 4; i++) acc4[i] = make_float4(0.f, 0.f, 0.f, 0.f);
#pragma unroll 8
            for (int k = 0; k < 64; k++) {
                float4 a  = *(const float4*)&qfT[k][tm0];
                float4 bv = *(const float4*)&kfT[k][sn0];
                FMA4(acc4[0], a.x, bv); FMA4(acc4[1], a.y, bv);
                FMA4(acc4[2], a.z, bv); FMA4(acc4[3], a.w, bv);
            }
#pragma unroll
            for (int i = 0; i < 4; i++) {
                const int t = tt0 + tm0 + i;
                const float iv = inv_s[tm0 + i];
                const int sg = s0 + sn0;
                float4 rr = acc4[i];
                rr.x = (sg + 0 <= t) ? rr.x * iv : 0.f;
                rr.y = (sg + 1 <= t) ? rr.y * iv : 0.f;
                rr.z = (sg + 2 <= t) ? rr.z * iv : 0.f;
                rr.w = (sg + 3 <= t) ? rr.w * iv : 0.f;
                *(float4*)(attb + (size_t)t * TDIM + sg) = rr;
            }
            __syncthreads();
        } else {
            const float4 z = make_float4(0.f, 0.f, 0.f, 0.f);
            const int t = tt0 + r;
#pragma unroll
            for (int u = 0; u < 4; u++)
                *(float4*)(attb + (size_t)t * TDIM + s0 + qq * 16 + 4 * u) = z;
        }
    }
}

// ---------------------------------------------------------------------------
extern "C" void kernel_launch(void* const* d_in, const int* in_sizes, int n_in,
                              void* d_out, int out_size, void* d_ws, size_t ws_size,
                              hipStream_t stream) {
    (void)in_sizes; (void)n_in; (void)out_size; (void)ws_size;
    const float* query = (const float*)d_in[0];
    const float* key   = (const float*)d_in[1];
    const float* value = (const float*)d_in[2];
    const float* Wq    = (const float*)d_in[3];
    const float* Wk    = (const float*)d_in[4];
    const float* Wv    = (const float*)d_in[5];
    const float* Wg    = (const float*)d_in[6];
    const float* bg    = (const float*)d_in[7];
    const float* Wo    = (const float*)d_in[8];
    float* out = (float*)d_out;                  // [B,T,M]
    float* att = (float*)d_out + 2097152;        // [B,H,T,T]
    float* ws  = (float*)d_ws;
    float* qf    = ws + OFF_QF;
    float* kf    = ws + OFF_KF;
    float* vg    = ws + OFF_VG;
    float* numer = ws + OFF_NU;
    float* den   = ws + OFF_DEN;
    float* ksum  = ws + OFF_KSUM;
    float* kv    = ws + OFF_KV;

    dim3 gemm_grid(32, 8), blk(256);
    gemm_k<0><<<gemm_grid, blk, 0, stream>>>(query, Wq, nullptr, nullptr, qf);
    gemm_k<0><<<gemm_grid, blk, 0, stream>>>(key, Wk, nullptr, nullptr, kf);
    gemm_k<2><<<gemm_grid, blk, 0, stream>>>(value, Wv, Wg, bg, vg);
    chunksum_k<<<dim3(32, 16), blk, 0, stream>>>(kf, vg, kv, ksum);
    prefix_k<<<dim3(32), blk, 0, stream>>>(kv, ksum);
    chunkout_k<<<dim3(32, 16), blk, 0, stream>>>(qf, kf, vg, kv, ksum, numer, den);
    attmap_k<<<dim3(32, 16), blk, 0, stream>>>(qf, kf, den, att);
    gemm_k<1><<<gemm_grid, blk, 0, stream>>>(numer, Wo, nullptr, nullptr, out);
}

// Round 2
// 337.717 us; speedup vs baseline: 1.5777x; 1.5777x over previous
//
#include <hip/hip_runtime.h>
#include <cstdint>

#define TDIM 1024
#define BDIM 4
#define MDIM 512
#define HDIM 8
#define EPSF 1e-6f

// ---- workspace layout ----
// float region (indices into (float*)d_ws):
#define OFF_QF   0u          // [4096,512]
#define OFF_KF   2097152u    // [4096,512]
#define OFF_VG   4194304u    // [4096,512]
#define OFF_DEN  6291456u    // [32,1024]
#define OFF_KSUM 6324224u    // [32,16,64]
#define OFF_KV   6356992u    // [32,16,64,64]
#define FLOAT_END 8454144u   // = 33,816,576 bytes
// ushort (bf16) region, starting at byte 33,816,576 (16B aligned):
#define UOFF_QB 0u           // [4096,512]
#define UOFF_KB 2097152u
#define UOFF_VB 4194304u
#define UOFF_NB 6291456u     // normalized numerator bf16 [4096,512]
#define UOFF_WQ 8388608u     // transposed weights [n][k], 512x512 each
#define UOFF_WK 8650752u
#define UOFF_WV 8912896u
#define UOFF_WG 9175040u
#define UOFF_WO 9437184u
// total ws: 33,816,576 + 19,398,656 = 53,215,232 bytes (~50.8 MB)

typedef short bf16x8 __attribute__((ext_vector_type(8)));
typedef float f32x4  __attribute__((ext_vector_type(4)));

__device__ __forceinline__ float phi_f(float x)  { return x > 0.f ? x + 1.f : __expf(x); }
__device__ __forceinline__ float sigm_f(float x) { return 1.f / (1.f + __expf(-x)); }
__device__ __forceinline__ unsigned short f2b(float x) {
    union { float f; unsigned u; } v; v.f = x;
    return (unsigned short)((v.u + 0x7FFFu + ((v.u >> 16) & 1u)) >> 16);
}
__device__ __forceinline__ float dot4(float4 a, float4 b) {
    return a.x * b.x + a.y * b.y + a.z * b.z + a.w * b.w;
}
#define FMA4(ACC, S, V) do { (ACC).x += (S)*(V).x; (ACC).y += (S)*(V).y; \
                             (ACC).z += (S)*(V).z; (ACC).w += (S)*(V).w; } while (0)

// ---------------------------------------------------------------------------
// cast fp32 -> bf16, 4 elems/thread
// ---------------------------------------------------------------------------
__global__ __launch_bounds__(256) void cast_k(const float* __restrict__ in,
                                              unsigned short* __restrict__ out) {
    const int i = blockIdx.x * 256 + threadIdx.x;
    float4 x = ((const float4*)in)[i];
    ushort4 o;
    o.x = f2b(x.x); o.y = f2b(x.y); o.z = f2b(x.z); o.w = f2b(x.w);
    ((ushort4*)out)[i] = o;
}

// ---------------------------------------------------------------------------
// cast + transpose weight: W[512 k][512 n] fp32 -> Wt[512 n][512 k] bf16
// 32x32 tiles
// ---------------------------------------------------------------------------
__global__ __launch_bounds__(256) void castwt_k(const float* __restrict__ W,
                                                unsigned short* __restrict__ Wt) {
    __shared__ unsigned short tile[32][36];
    const int t = threadIdx.x;
    const int r0 = blockIdx.y * 32, c0 = blockIdx.x * 32;
    {
        const int r = t >> 3, c4 = (t & 7) * 4;
        float4 x = *(const float4*)(W + (size_t)(r0 + r) * 512 + c0 + c4);
        tile[c4 + 0][r] = f2b(x.x); tile[c4 + 1][r] = f2b(x.y);
        tile[c4 + 2][r] = f2b(x.z); tile[c4 + 3][r] = f2b(x.w);
    }
    __syncthreads();
    const int c = t >> 3, r4 = (t & 7) * 4;
    ushort4 o;
    o.x = tile[c][r4 + 0]; o.y = tile[c][r4 + 1];
    o.z = tile[c][r4 + 2]; o.w = tile[c][r4 + 3];
    *(ushort4*)(Wt + (size_t)(c0 + c) * 512 + r0 + r4) = o;
}

// ---------------------------------------------------------------------------
// bf16 MFMA GEMM: out[4096,512](fp32) = A[4096,512](bf16) @ Bt^T
//   Bt is [512 n][512 k] bf16 (pre-transposed).
// MODE 0: phi epilogue   MODE 1: plain   MODE 2: dual -> A@B0 * 2*sigmoid(A@B1+bias)
// tile 64x64, BK=64, 256 threads = 4 waves (wave w -> rows w*16..w*16+15)
// LDS frag-ordered + XOR-swizzled: unit (m, c) at [(c*64 + (m^c))*8] bf16,
//   unit content = A[m][c*8 .. c*8+7] of the 64-wide K slice.
// ---------------------------------------------------------------------------
template <int MODE>
__global__ __launch_bounds__(256) void mgemm_k(const unsigned short* __restrict__ A,
                                               const unsigned short* __restrict__ B0t,
                                               const unsigned short* __restrict__ B1t,
                                               const float* __restrict__ bias,
                                               float* __restrict__ out) {
    extern __shared__ unsigned short smem[];
    unsigned short* As  = smem;            // 4096 elems = 8 KB
    unsigned short* Bs  = smem + 4096;     // 8 KB
    unsigned short* Bs2 = smem + 8192;     // 8 KB (MODE 2 only)
    const int tid  = threadIdx.x;
    const int row0 = blockIdx.x * 64;
    const int n0   = blockIdx.y * 64;
    const int w    = tid >> 6, lane = tid & 63;
    const int cc   = tid & 7,  rr   = tid >> 3;   // staging: unit col / row
    const int fm   = lane & 15, fq = lane >> 4;   // fragment indices

    f32x4 acc[4], acc2[4];
#pragma unroll
    for (int i = 0; i < 4; i++) {
        acc[i]  = (f32x4){0.f, 0.f, 0.f, 0.f};
        acc2[i] = (f32x4){0.f, 0.f, 0.f, 0.f};
    }

    for (int kt = 0; kt < 512; kt += 64) {
        // stage A (units (rr,cc) and (rr+32,cc)), B likewise
        {
            const unsigned short* ap = A + (size_t)(row0 + rr) * 512 + kt + cc * 8;
            *(int4*)&As[(cc * 64 + (rr ^ cc)) * 8]        = *(const int4*)ap;
            *(int4*)&As[(cc * 64 + ((rr + 32) ^ cc)) * 8] = *(const int4*)(ap + 32 * 512);
            const unsigned short* bp = B0t + (size_t)(n0 + rr) * 512 + kt + cc * 8;
            *(int4*)&Bs[(cc * 64 + (rr ^ cc)) * 8]        = *(const int4*)bp;
            *(int4*)&Bs[(cc * 64 + ((rr + 32) ^ cc)) * 8] = *(const int4*)(bp + 32 * 512);
            if (MODE == 2) {
                const unsigned short* gp = B1t + (size_t)(n0 + rr) * 512 + kt + cc * 8;
                *(int4*)&Bs2[(cc * 64 + (rr ^ cc)) * 8]        = *(const int4*)gp;
                *(int4*)&Bs2[(cc * 64 + ((rr + 32) ^ cc)) * 8] = *(const int4*)(gp + 32 * 512);
            }
        }
        __syncthreads();
#pragma unroll
        for (int j = 0; j < 2; j++) {
            const int c_ = j * 4 + fq;
            bf16x8 af = *(const bf16x8*)&As[(c_ * 64 + ((w * 16 + fm) ^ c_)) * 8];
#pragma unroll
            for (int nb = 0; nb < 4; nb++) {
                bf16x8 bfv = *(const bf16x8*)&Bs[(c_ * 64 + ((nb * 16 + fm) ^ c_)) * 8];
                acc[nb] = __builtin_amdgcn_mfma_f32_16x16x32_bf16(af, bfv, acc[nb], 0, 0, 0);
                if (MODE == 2) {
                    bf16x8 bgv = *(const bf16x8*)&Bs2[(c_ * 64 + ((nb * 16 + fm) ^ c_)) * 8];
                    acc2[nb] = __builtin_amdgcn_mfma_f32_16x16x32_bf16(af, bgv, acc2[nb], 0, 0, 0);
                }
            }
        }
        __syncthreads();
    }

    // epilogue: C/D layout col = lane&15, row = (lane>>4)*4 + r
#pragma unroll
    for (int nb = 0; nb < 4; nb++) {
        const int col = n0 + nb * 16 + fm;
        float bb = 0.f;
        if (MODE == 2) bb = bias[col];
#pragma unroll
        for (int r = 0; r < 4; r++) {
            const int row = row0 + w * 16 + fq * 4 + r;
            float v = acc[nb][r];
            if (MODE == 0)      v = phi_f(v);
            else if (MODE == 2) v *= 2.f * sigm_f(acc2[nb][r] + bb);
            out[(size_t)row * 512 + col] = v;
        }
    }
}

// ---------------------------------------------------------------------------
// K2a: per-(b,h,chunk) sums: kv[k][v] = sum_t kf[t][k]*vg[t][v]; ksum[k]
// ---------------------------------------------------------------------------
__global__ __launch_bounds__(256) void chunksum_k(const float* __restrict__ kf,
                                                  const float* __restrict__ vg,
                                                  float* __restrict__ kv,
                                                  float* __restrict__ ksum) {
    __shared__ __align__(16) float kf_c[64][68];
    __shared__ __align__(16) float vg_c[64][68];
    const int tid = threadIdx.x;
    const int bh = blockIdx.x, c = blockIdx.y;
    const int b = bh >> 3, h = bh & 7;
    const int r = tid >> 2, qq = tid & 3;
    const size_t rowbase = ((size_t)(b * TDIM + c * 64 + r)) * 512 + h * 64 + qq * 16;
#pragma unroll
    for (int u = 0; u < 4; u++) {
        *(float4*)&kf_c[r][qq * 16 + 4 * u] = *(const float4*)(kf + rowbase + 4 * u);
        *(float4*)&vg_c[r][qq * 16 + 4 * u] = *(const float4*)(vg + rowbase + 4 * u);
    }
    __syncthreads();
    const int k0 = (tid >> 4) * 4;
    const int v0 = (tid & 15) * 4;
    float4 a4[4];
#pragma unroll
    for (int i = 0; i < 4; i++) a4[i] = make_float4(0.f, 0.f, 0.f, 0.f);
    for (int t = 0; t < 64; t++) {
        float4 kk4 = *(const float4*)&kf_c[t][k0];
        float4 vv  = *(const float4*)&vg_c[t][v0];
        FMA4(a4[0], kk4.x, vv); FMA4(a4[1], kk4.y, vv);
        FMA4(a4[2], kk4.z, vv); FMA4(a4[3], kk4.w, vv);
    }
    const size_t base = (size_t)(bh * 16 + c) * 64;
#pragma unroll
    for (int i = 0; i < 4; i++)
        *(float4*)(kv + (base + k0 + i) * 64 + v0) = a4[i];
    if (tid < 64) {
        float s = 0.f;
        for (int t = 0; t < 64; t++) s += kf_c[t][tid];
        ksum[base + tid] = s;
    }
}

// ---------------------------------------------------------------------------
// K2b: in-place exclusive prefix over the 16 chunks (per bh)
// ---------------------------------------------------------------------------
__global__ __launch_bounds__(256) void prefix_k(float* __restrict__ kv,
                                                float* __restrict__ ksum) {
    const int tid = threadIdx.x;
    const int bh = blockIdx.x;
    float4 run[4];
#pragma unroll
    for (int u = 0; u < 4; u++) run[u] = make_float4(0.f, 0.f, 0.f, 0.f);
    const int d0 = tid * 16;
    for (int c = 0; c < 16; c++) {
        float* p = kv + (size_t)(bh * 16 + c) * 4096 + d0;
#pragma unroll
        for (int u = 0; u < 4; u++) {
            float4 x = *(float4*)(p + 4 * u);
            *(float4*)(p + 4 * u) = run[u];
            run[u].x += x.x; run[u].y += x.y; run[u].z += x.z; run[u].w += x.w;
        }
    }
    if (tid < 64) {
        float r2 = 0.f;
        for (int c = 0; c < 16; c++) {
            float* p = ksum + (size_t)(bh * 16 + c) * 64 + tid;
            float x = *p; *p = r2; r2 += x;
        }
    }
}

// ---------------------------------------------------------------------------
// K2c: per-(b,h,chunk): denom + normalized numerator (bf16 out)
// ---------------------------------------------------------------------------
__global__ __launch_bounds__(256) void chunkout_k(const float* __restrict__ qf,
                                                  const float* __restrict__ kfp,
                                                  const float* __restrict__ vgp,
                                                  const float* __restrict__ kv,
                                                  const float* __restrict__ ksum,
                                                  unsigned short* __restrict__ numer,
                                                  float* __restrict__ denom) {
    __shared__ __align__(16) float qf_c[64][68];
    __shared__ __align__(16) float kf_c[64][68];
    __shared__ __align__(16) float vgT[64][68];
    __shared__ __align__(16) float kvT[64][68];
    __shared__ __align__(16) float sc[64][68];
    __shared__ __align__(16) float kpre_s[64];
    __shared__ __align__(16) float den_s[64];
    const int tid = threadIdx.x;
    const int bh = blockIdx.x, c = blockIdx.y;
    const int b = bh >> 3, h = bh & 7;
    const int r = tid >> 2, qq = tid & 3;
    {
        const size_t rowbase = ((size_t)(b * TDIM + c * 64 + r)) * 512 + h * 64 + qq * 16;
#pragma unroll
        for (int u = 0; u < 4; u++) {
            *(float4*)&qf_c[r][qq * 16 + 4 * u] = *(const float4*)(qf + rowbase + 4 * u);
            *(float4*)&kf_c[r][qq * 16 + 4 * u] = *(const float4*)(kfp + rowbase + 4 * u);
            float4 vv = *(const float4*)(vgp + rowbase + 4 * u);
            vgT[qq * 16 + 4 * u + 0][r] = vv.x; vgT[qq * 16 + 4 * u + 1][r] = vv.y;
            vgT[qq * 16 + 4 * u + 2][r] = vv.z; vgT[qq * 16 + 4 * u + 3][r] = vv.w;
        }
        const size_t kvbase = ((size_t)(bh * 16 + c) * 64 + r) * 64 + qq * 16;
#pragma unroll
        for (int u = 0; u < 4; u++) {
            float4 x = *(const float4*)(kv + kvbase + 4 * u);
            kvT[qq * 16 + 4 * u + 0][r] = x.x; kvT[qq * 16 + 4 * u + 1][r] = x.y;
            kvT[qq * 16 + 4 * u + 2][r] = x.z; kvT[qq * 16 + 4 * u + 3][r] = x.w;
        }
        if (tid < 64) kpre_s[tid] = ksum[(size_t)(bh * 16 + c) * 64 + tid];
    }
    __syncthreads();
    const int tt = tid >> 2, sq = tid & 3;
    float4 qreg[16];
#pragma unroll
    for (int u = 0; u < 16; u++) qreg[u] = *(const float4*)&qf_c[tt][4 * u];
    // phase A: intra-chunk causal scores
    for (int si = 0; si < 16; si++) {
        const int s = sq * 16 + si;
        float val = 0.f;
        if (s <= tt) {
#pragma unroll
            for (int u = 0; u < 16; u++)
                val += dot4(qreg[u], *(const float4*)&kf_c[s][4 * u]);
        }
        sc[tt][s] = val;
    }
    __syncthreads();
    float4 screg[16];
#pragma unroll
    for (int u = 0; u < 16; u++) screg[u] = *(const float4*)&sc[tt][4 * u];
    if (sq == 0) {
        float den = 0.f;
#pragma unroll
        for (int u = 0; u < 16; u++) {
            den += dot4(qreg[u], *(const float4*)&kpre_s[4 * u]);
            den += screg[u].x + screg[u].y + screg[u].z + screg[u].w;
        }
        den_s[tt] = den;
        denom[(size_t)bh * TDIM + c * 64 + tt] = den;
    }
    __syncthreads();
    const float inv = 1.f / (den_s[tt] + EPSF);
    for (int vi = 0; vi < 16; vi++) {
        const int v = sq * 16 + vi;
        float a = 0.f;
#pragma unroll
        for (int u = 0; u < 16; u++) {
            a += dot4(qreg[u], *(const float4*)&kvT[v][4 * u]);
            a += dot4(screg[u], *(const float4*)&vgT[v][4 * u]);
        }
        numer[((size_t)(b * TDIM + c * 64 + tt)) * 512 + h * 64 + v] = f2b(a * inv);
    }
}

// ---------------------------------------------------------------------------
// K3: att_map: scores recomputed as 64x64 tiles, normalized by denom, causal
// ---------------------------------------------------------------------------
__global__ __launch_bounds__(256) void attmap_k(const float* __restrict__ qf,
                                                const float* __restrict__ kfp,
                                                const float* __restrict__ denom,
                                                float* __restrict__ att) {
    __shared__ __align__(16) float qfT[64][68];
    __shared__ __align__(16) float kfT[64][68];
    __shared__ __align__(16) float inv_s[64];
    const int tid = threadIdx.x;
    const int bh = blockIdx.x;
    const int tt0 = blockIdx.y * 64;
    const int b = bh >> 3, h = bh & 7;
    const int r = tid >> 2, qq = tid & 3;
    {
        const size_t rowbase = ((size_t)(b * TDIM + tt0 + r)) * 512 + h * 64 + qq * 16;
#pragma unroll
        for (int u = 0; u < 4; u++) {
            float4 x = *(const float4*)(qf + rowbase + 4 * u);
            qfT[qq * 16 + 4 * u + 0][r] = x.x; qfT[qq * 16 + 4 * u + 1][r] = x.y;
            qfT[qq * 16 + 4 * u + 2][r] = x.z; qfT[qq * 16 + 4 * u + 3][r] = x.w;
        }
        if (tid < 64) inv_s[tid] = 1.f / (denom[(size_t)bh * TDIM + tt0 + tid] + EPSF);
    }
    __syncthreads();
    float* attb = att + (size_t)bh * TDIM * TDIM;
    const int tm0 = (tid >> 4) * 4;
    const int sn0 = (tid & 15) * 4;
    for (int st = 0; st < 16; st++) {
        const int s0 = st * 64;
        if (s0 <= tt0 + 63) {
            const size_t rb = ((size_t)(b * TDIM + s0 + r)) * 512 + h * 64 + qq * 16;
#pragma unroll
            for (int u = 0; u < 4; u++) {
                float4 x = *(const float4*)(kfp + rb + 4 * u);
                kfT[qq * 16 + 4 * u + 0][r] = x.x; kfT[qq * 16 + 4 * u + 1][r] = x.y;
                kfT[qq * 16 + 4 * u + 2][r] = x.z; kfT[qq * 16 + 4 * u + 3][r] = x.w;
            }
            __syncthreads();
            float4 acc4[4];
#pragma unroll
            for (int i = 0; i < 4; i++) acc4[i] = make_float4(0.f, 0.f, 0.f, 0.f);
#pragma unroll 8
            for (int k = 0; k < 64; k++) {
                float4 a  = *(const float4*)&qfT[k][tm0];
                float4 bv = *(const float4*)&kfT[k][sn0];
                FMA4(acc4[0], a.x, bv); FMA4(acc4[1], a.y, bv);
                FMA4(acc4[2], a.z, bv); FMA4(acc4[3], a.w, bv);
            }
#pragma unroll
            for (int i = 0; i < 4; i++) {
                const int t = tt0 + tm0 + i;
                const float iv = inv_s[tm0 + i];
                const int sg = s0 + sn0;
                float4 rr = acc4[i];
                rr.x = (sg + 0 <= t) ? rr.x * iv : 0.f;
                rr.y = (sg + 1 <= t) ? rr.y * iv : 0.f;
                rr.z = (sg + 2 <= t) ? rr.z * iv : 0.f;
                rr.w = (sg + 3 <= t) ? rr.w * iv : 0.f;
                *(float4*)(attb + (size_t)t * TDIM + sg) = rr;
            }
            __syncthreads();
        } else {
            const float4 z = make_float4(0.f, 0.f, 0.f, 0.f);
            const int t = tt0 + r;
#pragma unroll
            for (int u = 0; u < 4; u++)
                *(float4*)(attb + (size_t)t * TDIM + s0 + qq * 16 + 4 * u) = z;
        }
    }
}

// ---------------------------------------------------------------------------
extern "C" void kernel_launch(void* const* d_in, const int* in_sizes, int n_in,
                              void* d_out, int out_size, void* d_ws, size_t ws_size,
                              hipStream_t stream) {
    (void)in_sizes; (void)n_in; (void)out_size; (void)ws_size;
    const float* query = (const float*)d_in[0];
    const float* key   = (const float*)d_in[1];
    const float* value = (const float*)d_in[2];
    const float* Wq    = (const float*)d_in[3];
    const float* Wk    = (const float*)d_in[4];
    const float* Wv    = (const float*)d_in[5];
    const float* Wg    = (const float*)d_in[6];
    const float* bg    = (const float*)d_in[7];
    const float* Wo    = (const float*)d_in[8];
    float* out = (float*)d_out;                  // [B,T,M]
    float* att = (float*)d_out + 2097152;        // [B,H,T,T]
    float* ws  = (float*)d_ws;
    float* qf    = ws + OFF_QF;
    float* kf    = ws + OFF_KF;
    float* vg    = ws + OFF_VG;
    float* den   = ws + OFF_DEN;
    float* ksum  = ws + OFF_KSUM;
    float* kv    = ws + OFF_KV;
    unsigned short* ub = (unsigned short*)((char*)d_ws + (size_t)FLOAT_END * 4);
    unsigned short* qb  = ub + UOFF_QB;
    unsigned short* kb  = ub + UOFF_KB;
    unsigned short* vb  = ub + UOFF_VB;
    unsigned short* nb  = ub + UOFF_NB;
    unsigned short* wqt = ub + UOFF_WQ;
    unsigned short* wkt = ub + UOFF_WK;
    unsigned short* wvt = ub + UOFF_WV;
    unsigned short* wgt = ub + UOFF_WG;
    unsigned short* wot = ub + UOFF_WO;

    dim3 blk(256);
    // casts
    cast_k<<<dim3(2048), blk, 0, stream>>>(query, qb);
    cast_k<<<dim3(2048), blk, 0, stream>>>(key,   kb);
    cast_k<<<dim3(2048), blk, 0, stream>>>(value, vb);
    castwt_k<<<dim3(16, 16), blk, 0, stream>>>(Wq, wqt);
    castwt_k<<<dim3(16, 16), blk, 0, stream>>>(Wk, wkt);
    castwt_k<<<dim3(16, 16), blk, 0, stream>>>(Wv, wvt);
    castwt_k<<<dim3(16, 16), blk, 0, stream>>>(Wg, wgt);
    castwt_k<<<dim3(16, 16), blk, 0, stream>>>(Wo, wot);
    // MFMA projections
    dim3 ggrid(64, 8);
    mgemm_k<0><<<ggrid, blk, 16384, stream>>>(qb, wqt, nullptr, nullptr, qf);
    mgemm_k<0><<<ggrid, blk, 16384, stream>>>(kb, wkt, nullptr, nullptr, kf);
    mgemm_k<2><<<ggrid, blk, 24576, stream>>>(vb, wvt, wgt, bg, vg);
    // chunked causal linear attention
    chunksum_k<<<dim3(32, 16), blk, 0, stream>>>(kf, vg, kv, ksum);
    prefix_k<<<dim3(32), blk, 0, stream>>>(kv, ksum);
    chunkout_k<<<dim3(32, 16), blk, 0, stream>>>(qf, kf, vg, kv, ksum, nb, den);
    // attention map
    attmap_k<<<dim3(32, 16), blk, 0, stream>>>(qf, kf, den, att);
    // output projection
    mgemm_k<1><<<ggrid, blk, 16384, stream>>>(nb, wot, nullptr, nullptr, out);
}

// Round 3
// 284.348 us; speedup vs baseline: 1.8738x; 1.1877x over previous
//
#include <hip/hip_runtime.h>
#include <cstdint>

#define TDIM 1024
#define BDIM 4
#define EPSF 1e-6f

// ---- workspace layout ----
// float region (indices into (float*)d_ws):
#define OFF_DEN   0u          // [32,1024]
#define OFF_KSUM  32768u      // [32,16,64]
#define OFF_KV    65536u      // [32,16,64,64]
#define FLOAT_BYTES 8650752u  // 2,162,688 floats
// ushort (bf16) region (indices into ushort*, after FLOAT_BYTES):
#define UOFF_QP 0u            // q proj bf16 [4096,512]
#define UOFF_KP 2097152u
#define UOFF_VP 4194304u
#define UOFF_NB 6291456u      // normalized numerator bf16 [4096,512]
#define UOFF_WQ 8388608u      // transposed weights [n][k] bf16, 512x512 each
#define UOFF_WK 8650752u
#define UOFF_WV 8912896u
#define UOFF_WG 9175040u
#define UOFF_WO 9437184u
// total ws = 8,650,752 + 19,398,656 = 28,049,408 bytes

typedef short bf16x8 __attribute__((ext_vector_type(8)));
typedef float f32x4  __attribute__((ext_vector_type(4)));
typedef unsigned short ushort_t;

union bfu { int4 i4; unsigned short us[8]; bf16x8 v; };

__device__ __forceinline__ float phi_f(float x)  { return x > 0.f ? x + 1.f : __expf(x); }
__device__ __forceinline__ float sigm_f(float x) { return 1.f / (1.f + __expf(-x)); }
__device__ __forceinline__ unsigned short f2b(float x) {
    union { float f; unsigned u; } v; v.f = x;
    return (unsigned short)((v.u + 0x7FFFu + ((v.u >> 16) & 1u)) >> 16);
}
__device__ __forceinline__ float b2f(unsigned short s) {
    union { unsigned u; float f; } v; v.u = (unsigned)s << 16; return v.f;
}
__device__ __forceinline__ int4 pack8(float4 a, float4 b) {
    bfu u;
    u.us[0] = f2b(a.x); u.us[1] = f2b(a.y); u.us[2] = f2b(a.z); u.us[3] = f2b(a.w);
    u.us[4] = f2b(b.x); u.us[5] = f2b(b.y); u.us[6] = f2b(b.z); u.us[7] = f2b(b.w);
    return u.i4;
}
#define FMA4(ACC, S, V) do { (ACC).x += (S)*(V).x; (ACC).y += (S)*(V).y; \
                             (ACC).z += (S)*(V).z; (ACC).w += (S)*(V).w; } while (0)

// ---------------------------------------------------------------------------
// cast + transpose all 5 weights: W[512 k][512 n] fp32 -> Wt[512 n][512 k] bf16
// grid (16,16,5)
// ---------------------------------------------------------------------------
__global__ __launch_bounds__(256) void castwt_all(const float* __restrict__ W0,
                                                  const float* __restrict__ W1,
                                                  const float* __restrict__ W2,
                                                  const float* __restrict__ W3,
                                                  const float* __restrict__ W4,
                                                  ushort_t* __restrict__ T0,
                                                  ushort_t* __restrict__ T1,
                                                  ushort_t* __restrict__ T2,
                                                  ushort_t* __restrict__ T3,
                                                  ushort_t* __restrict__ T4) {
    const float* W; ushort_t* Wt;
    switch (blockIdx.z) {
        case 0: W = W0; Wt = T0; break;
        case 1: W = W1; Wt = T1; break;
        case 2: W = W2; Wt = T2; break;
        case 3: W = W3; Wt = T3; break;
        default: W = W4; Wt = T4; break;
    }
    __shared__ unsigned short tile[32][36];
    const int t = threadIdx.x;
    const int r0 = blockIdx.y * 32, c0 = blockIdx.x * 32;
    {
        const int r = t >> 3, c4 = (t & 7) * 4;
        float4 x = *(const float4*)(W + (size_t)(r0 + r) * 512 + c0 + c4);
        tile[c4 + 0][r] = f2b(x.x); tile[c4 + 1][r] = f2b(x.y);
        tile[c4 + 2][r] = f2b(x.z); tile[c4 + 3][r] = f2b(x.w);
    }
    __syncthreads();
    const int c = t >> 3, r4 = (t & 7) * 4;
    ushort4 o;
    o.x = tile[c][r4 + 0]; o.y = tile[c][r4 + 1];
    o.z = tile[c][r4 + 2]; o.w = tile[c][r4 + 3];
    *(ushort4*)(Wt + (size_t)(c0 + c) * 512 + r0 + r4) = o;
}

// ---------------------------------------------------------------------------
// bf16 MFMA GEMM, 64x64 tile, BK=64, 4 waves.
// MODE 0: A fp32 (cast in staging), out bf16 phi
// MODE 2: A fp32, dual B, out bf16 = (A@B0)*2*sigmoid(A@B1+bias)
// MODE 1: A bf16, out fp32 plain
// ---------------------------------------------------------------------------
template <int MODE>
__global__ __launch_bounds__(256) void mgemm_k(const void* __restrict__ Ap,
                                               const ushort_t* __restrict__ B0t,
                                               const ushort_t* __restrict__ B1t,
                                               const float* __restrict__ bias,
                                               ushort_t* __restrict__ outb,
                                               float* __restrict__ outf) {
    extern __shared__ unsigned short smem[];
    unsigned short* As  = smem;            // 8 KB
    unsigned short* Bs  = smem + 4096;     // 8 KB
    unsigned short* Bs2 = smem + 8192;     // 8 KB (MODE 2 only)
    const int tid  = threadIdx.x;
    const int row0 = blockIdx.x * 64;
    const int n0   = blockIdx.y * 64;
    const int w    = tid >> 6, lane = tid & 63;
    const int cc   = tid & 7,  rr   = tid >> 3;
    const int fm   = lane & 15, fq = lane >> 4;

    f32x4 acc[4], acc2[4];
#pragma unroll
    for (int i = 0; i < 4; i++) {
        acc[i]  = (f32x4){0.f, 0.f, 0.f, 0.f};
        acc2[i] = (f32x4){0.f, 0.f, 0.f, 0.f};
    }

    for (int kt = 0; kt < 512; kt += 64) {
        if (MODE == 1) {
            const ushort_t* ap = (const ushort_t*)Ap + (size_t)(row0 + rr) * 512 + kt + cc * 8;
            *(int4*)&As[(cc * 64 + (rr ^ cc)) * 8]        = *(const int4*)ap;
            *(int4*)&As[(cc * 64 + ((rr + 32) ^ cc)) * 8] = *(const int4*)(ap + 32 * 512);
        } else {
            const float* ap = (const float*)Ap + (size_t)(row0 + rr) * 512 + kt + cc * 8;
            *(int4*)&As[(cc * 64 + (rr ^ cc)) * 8] =
                pack8(*(const float4*)ap, *(const float4*)(ap + 4));
            const float* ap2 = ap + 32 * 512;
            *(int4*)&As[(cc * 64 + ((rr + 32) ^ cc)) * 8] =
                pack8(*(const float4*)ap2, *(const float4*)(ap2 + 4));
        }
        const ushort_t* bp = B0t + (size_t)(n0 + rr) * 512 + kt + cc * 8;
        *(int4*)&Bs[(cc * 64 + (rr ^ cc)) * 8]        = *(const int4*)bp;
        *(int4*)&Bs[(cc * 64 + ((rr + 32) ^ cc)) * 8] = *(const int4*)(bp + 32 * 512);
        if (MODE == 2) {
            const ushort_t* gp = B1t + (size_t)(n0 + rr) * 512 + kt + cc * 8;
            *(int4*)&Bs2[(cc * 64 + (rr ^ cc)) * 8]        = *(const int4*)gp;
            *(int4*)&Bs2[(cc * 64 + ((rr + 32) ^ cc)) * 8] = *(const int4*)(gp + 32 * 512);
        }
        __syncthreads();
#pragma unroll
        for (int j = 0; j < 2; j++) {
            const int c_ = j * 4 + fq;
            bf16x8 af = *(const bf16x8*)&As[(c_ * 64 + ((w * 16 + fm) ^ c_)) * 8];
#pragma unroll
            for (int nb = 0; nb < 4; nb++) {
                bf16x8 bfv = *(const bf16x8*)&Bs[(c_ * 64 + ((nb * 16 + fm) ^ c_)) * 8];
                acc[nb] = __builtin_amdgcn_mfma_f32_16x16x32_bf16(af, bfv, acc[nb], 0, 0, 0);
                if (MODE == 2) {
                    bf16x8 bgv = *(const bf16x8*)&Bs2[(c_ * 64 + ((nb * 16 + fm) ^ c_)) * 8];
                    acc2[nb] = __builtin_amdgcn_mfma_f32_16x16x32_bf16(af, bgv, acc2[nb], 0, 0, 0);
                }
            }
        }
        __syncthreads();
    }

#pragma unroll
    for (int nb = 0; nb < 4; nb++) {
        const int col = n0 + nb * 16 + fm;
        float bb = 0.f;
        if (MODE == 2) bb = bias[col];
#pragma unroll
        for (int r = 0; r < 4; r++) {
            const int row = row0 + w * 16 + fq * 4 + r;
            float v = acc[nb][r];
            if (MODE == 0)      outb[(size_t)row * 512 + col] = f2b(phi_f(v));
            else if (MODE == 2) outb[(size_t)row * 512 + col] =
                                    f2b(v * 2.f * sigm_f(acc2[nb][r] + bb));
            else                outf[(size_t)row * 512 + col] = v;
        }
    }
}

// ---------------------------------------------------------------------------
// K2a: per-(b,h,chunk) sums from bf16 projections:
//   kv[k][v] = sum_t kf[t][k]*vg[t][v]; ksum[k] = sum_t kf[t][k]
// ---------------------------------------------------------------------------
__global__ __launch_bounds__(256) void chunksum_k(const ushort_t* __restrict__ kb,
                                                  const ushort_t* __restrict__ vb,
                                                  float* __restrict__ kv,
                                                  float* __restrict__ ksum) {
    __shared__ __align__(16) float kf_c[64][68];
    __shared__ __align__(16) float vg_c[64][68];
    const int tid = threadIdx.x;
    const int bh = blockIdx.x, c = blockIdx.y;
    const int b = bh >> 3, h = bh & 7;
    const int r = tid >> 2, qq = tid & 3;
    {
        const size_t rowbase = ((size_t)(b * TDIM + c * 64 + r)) * 512 + h * 64 + qq * 16;
        bfu k0, k1, v0, v1;
        k0.i4 = *(const int4*)(kb + rowbase);
        k1.i4 = *(const int4*)(kb + rowbase + 8);
        v0.i4 = *(const int4*)(vb + rowbase);
        v1.i4 = *(const int4*)(vb + rowbase + 8);
#pragma unroll
        for (int j = 0; j < 8; j++) {
            kf_c[r][qq * 16 + j]     = b2f(k0.us[j]);
            kf_c[r][qq * 16 + 8 + j] = b2f(k1.us[j]);
            vg_c[r][qq * 16 + j]     = b2f(v0.us[j]);
            vg_c[r][qq * 16 + 8 + j] = b2f(v1.us[j]);
        }
    }
    __syncthreads();
    const int k0i = (tid >> 4) * 4;
    const int v0i = (tid & 15) * 4;
    float4 a4[4];
#pragma unroll
    for (int i = 0; i < 4; i++) a4[i] = make_float4(0.f, 0.f, 0.f, 0.f);
    for (int t = 0; t < 64; t++) {
        float4 kk4 = *(const float4*)&kf_c[t][k0i];
        float4 vv  = *(const float4*)&vg_c[t][v0i];
        FMA4(a4[0], kk4.x, vv); FMA4(a4[1], kk4.y, vv);
        FMA4(a4[2], kk4.z, vv); FMA4(a4[3], kk4.w, vv);
    }
    const size_t base = (size_t)(bh * 16 + c) * 64;
#pragma unroll
    for (int i = 0; i < 4; i++)
        *(float4*)(kv + (base + k0i + i) * 64 + v0i) = a4[i];
    if (tid < 64) {
        float s = 0.f;
        for (int t = 0; t < 64; t++) s += kf_c[t][tid];
        ksum[base + tid] = s;
    }
}

// ---------------------------------------------------------------------------
// K2b: in-place exclusive prefix over the 16 chunks (per bh)
// ---------------------------------------------------------------------------
__global__ __launch_bounds__(256) void prefix_k(float* __restrict__ kv,
                                                float* __restrict__ ksum) {
    const int tid = threadIdx.x;
    const int bh = blockIdx.x;
    float4 run[4];
#pragma unroll
    for (int u = 0; u < 4; u++) run[u] = make_float4(0.f, 0.f, 0.f, 0.f);
    const int d0 = tid * 16;
    for (int c = 0; c < 16; c++) {
        float* p = kv + (size_t)(bh * 16 + c) * 4096 + d0;
#pragma unroll
        for (int u = 0; u < 4; u++) {
            float4 x = *(float4*)(p + 4 * u);
            *(float4*)(p + 4 * u) = run[u];
            run[u].x += x.x; run[u].y += x.y; run[u].z += x.z; run[u].w += x.w;
        }
    }
    if (tid < 64) {
        float r2 = 0.f;
        for (int c = 0; c < 16; c++) {
            float* p = ksum + (size_t)(bh * 16 + c) * 64 + tid;
            float x = *p; *p = r2; r2 += x;
        }
    }
}

// ---------------------------------------------------------------------------
// K2c (MFMA): per-(b,h,chunk):
//   S = Q.K^T (causal-masked), denom = rowsum(S) + q.kpre,
//   numer = Q.KVpre^T + P.V^T, write bf16 numer*inv(denom) and fp32 denom.
// 256 threads = 4 waves; wave w covers rows w*16..w*16+15.
// ---------------------------------------------------------------------------
__global__ __launch_bounds__(256) void chunkout_k(const ushort_t* __restrict__ qb,
                                                  const ushort_t* __restrict__ kb,
                                                  const ushort_t* __restrict__ vb,
                                                  const float* __restrict__ kvp,
                                                  const float* __restrict__ ksum,
                                                  ushort_t* __restrict__ nbo,
                                                  float* __restrict__ denom) {
    __shared__ __align__(16) unsigned short qs[4096];
    __shared__ __align__(16) unsigned short ks[4096];
    __shared__ __align__(16) unsigned short vs[4096];   // V^T frag-ordered
    __shared__ __align__(16) unsigned short kvs[4096];  // KVpre^T frag-ordered
    __shared__ __align__(16) float sc[64][68];
    __shared__ __align__(16) float kpre[64];
    __shared__ __align__(16) float ps[64][4];
    __shared__ __align__(16) float inv_s[64];
    const int tid = threadIdx.x;
    const int bh = blockIdx.x, c = blockIdx.y;
    const int b = bh >> 3, h = bh & 7;
    const int w = tid >> 6, lane = tid & 63;
    const int fm = lane & 15, fq = lane >> 4;

    // phase 0: staging
    {
        const int rr = tid >> 3, cc = tid & 7;
        const ushort_t* qp = qb + ((size_t)(b * TDIM + c * 64 + rr)) * 512 + h * 64 + cc * 8;
        const ushort_t* kp = kb + ((size_t)(b * TDIM + c * 64 + rr)) * 512 + h * 64 + cc * 8;
        *(int4*)&qs[(cc * 64 + (rr ^ cc)) * 8]        = *(const int4*)qp;
        *(int4*)&qs[(cc * 64 + ((rr + 32) ^ cc)) * 8] = *(const int4*)(qp + 32 * 512);
        *(int4*)&ks[(cc * 64 + (rr ^ cc)) * 8]        = *(const int4*)kp;
        *(int4*)&ks[(cc * 64 + ((rr + 32) ^ cc)) * 8] = *(const int4*)(kp + 32 * 512);
        const int v = tid & 63, su0 = (tid >> 6) * 2;
#pragma unroll
        for (int e = 0; e < 2; e++) {
            const int su = su0 + e;
            bfu t1;
#pragma unroll
            for (int j = 0; j < 8; j++)
                t1.us[j] = vb[((size_t)(b * TDIM + c * 64 + su * 8 + j)) * 512 + h * 64 + v];
            *(int4*)&vs[(su * 64 + (v ^ su)) * 8] = t1.i4;
            bfu t2;
            const float* kvrow = kvp + (size_t)(bh * 16 + c) * 4096 + v;
#pragma unroll
            for (int j = 0; j < 8; j++)
                t2.us[j] = f2b(kvrow[(su * 8 + j) * 64]);
            *(int4*)&kvs[(su * 64 + (v ^ su)) * 8] = t2.i4;
        }
        if (tid < 64) kpre[tid] = ksum[(size_t)(bh * 16 + c) * 64 + tid];
    }
    __syncthreads();

    // phase 1: S = Q.K^T, mask, -> sc
    {
        f32x4 sa[4];
#pragma unroll
        for (int i = 0; i < 4; i++) sa[i] = (f32x4){0.f, 0.f, 0.f, 0.f};
#pragma unroll
        for (int j = 0; j < 2; j++) {
            const int cu = j * 4 + fq;
            bf16x8 aq = *(const bf16x8*)&qs[(cu * 64 + ((w * 16 + fm) ^ cu)) * 8];
#pragma unroll
            for (int nb = 0; nb < 4; nb++) {
                bf16x8 bk = *(const bf16x8*)&ks[(cu * 64 + ((nb * 16 + fm) ^ cu)) * 8];
                sa[nb] = __builtin_amdgcn_mfma_f32_16x16x32_bf16(aq, bk, sa[nb], 0, 0, 0);
            }
        }
#pragma unroll
        for (int nb = 0; nb < 4; nb++) {
            const int s_l = nb * 16 + fm;
#pragma unroll
            for (int r = 0; r < 4; r++) {
                const int t_l = w * 16 + fq * 4 + r;
                sc[t_l][s_l] = (s_l <= t_l) ? sa[nb][r] : 0.f;
            }
        }
    }
    __syncthreads();

    // phase 2: denom
    {
        const int rw = tid >> 2, sq = tid & 3;
        float p = 0.f;
#pragma unroll
        for (int s = sq * 16; s < sq * 16 + 16; s++) p += sc[rw][s];
#pragma unroll
        for (int kd = sq * 16; kd < sq * 16 + 16; kd++) {
            const int cu = kd >> 3;
            p += b2f(qs[(cu * 64 + (rw ^ cu)) * 8 + (kd & 7)]) * kpre[kd];
        }
        ps[rw][sq] = p;
    }
    __syncthreads();
    {
        const int rw = tid >> 2, sq = tid & 3;
        if (sq == 0) {
            float den = ps[rw][0] + ps[rw][1] + ps[rw][2] + ps[rw][3];
            denom[(size_t)bh * TDIM + c * 64 + rw] = den;
            inv_s[rw] = 1.f / (den + EPSF);
        }
    }
    __syncthreads();

    // phase 3: numer = Q.KVpre^T + P.V^T, scaled by inv
    {
        f32x4 oa[4];
#pragma unroll
        for (int i = 0; i < 4; i++) oa[i] = (f32x4){0.f, 0.f, 0.f, 0.f};
        bf16x8 aq[2], ap_[2];
#pragma unroll
        for (int j = 0; j < 2; j++) {
            const int cu = j * 4 + fq;
            aq[j] = *(const bf16x8*)&qs[(cu * 64 + ((w * 16 + fm) ^ cu)) * 8];
            bfu t;
#pragma unroll
            for (int e2 = 0; e2 < 8; e2++) t.us[e2] = f2b(sc[w * 16 + fm][cu * 8 + e2]);
            ap_[j] = t.v;
        }
#pragma unroll
        for (int nb = 0; nb < 4; nb++) {
#pragma unroll
            for (int j = 0; j < 2; j++) {
                const int cu = j * 4 + fq;
                bf16x8 bkv = *(const bf16x8*)&kvs[(cu * 64 + ((nb * 16 + fm) ^ cu)) * 8];
                bf16x8 bv  = *(const bf16x8*)&vs[(cu * 64 + ((nb * 16 + fm) ^ cu)) * 8];
                oa[nb] = __builtin_amdgcn_mfma_f32_16x16x32_bf16(aq[j], bkv, oa[nb], 0, 0, 0);
                oa[nb] = __builtin_amdgcn_mfma_f32_16x16x32_bf16(ap_[j], bv, oa[nb], 0, 0, 0);
            }
        }
#pragma unroll
        for (int nb = 0; nb < 4; nb++) {
            const int vcol = nb * 16 + fm;
#pragma unroll
            for (int r = 0; r < 4; r++) {
                const int t_l = w * 16 + fq * 4 + r;
                const float val = oa[nb][r] * inv_s[t_l];
                nbo[((size_t)(b * TDIM + c * 64 + t_l)) * 512 + h * 64 + vcol] = f2b(val);
            }
        }
    }
}

// ---------------------------------------------------------------------------
// K3 (MFMA): att_map tiles = (Q.K^T)*inv(denom), causal; zero-fill above diag
// ---------------------------------------------------------------------------
__global__ __launch_bounds__(256) void attmap_k(const ushort_t* __restrict__ qb,
                                                const ushort_t* __restrict__ kb,
                                                const float* __restrict__ denom,
                                                float* __restrict__ att) {
    __shared__ __align__(16) unsigned short qs[4096];
    __shared__ __align__(16) unsigned short ks[4096];
    __shared__ __align__(16) float inv_s[64];
    const int tid = threadIdx.x;
    const int bh = blockIdx.x, diag = blockIdx.y;
    const int tt0 = diag * 64;
    const int b = bh >> 3, h = bh & 7;
    const int w = tid >> 6, lane = tid & 63;
    const int fm = lane & 15, fq = lane >> 4;
    const int rr = tid >> 3, cc = tid & 7;
    {
        const ushort_t* qp = qb + ((size_t)(b * TDIM + tt0 + rr)) * 512 + h * 64 + cc * 8;
        *(int4*)&qs[(cc * 64 + (rr ^ cc)) * 8]        = *(const int4*)qp;
        *(int4*)&qs[(cc * 64 + ((rr + 32) ^ cc)) * 8] = *(const int4*)(qp + 32 * 512);
        if (tid < 64) inv_s[tid] = 1.f / (denom[(size_t)bh * TDIM + tt0 + tid] + EPSF);
    }
    float* attb = att + (size_t)bh * TDIM * TDIM;
    for (int st = 0; st <= diag; st++) {
        const int s0 = st * 64;
        const ushort_t* kp = kb + ((size_t)(b * TDIM + s0 + rr)) * 512 + h * 64 + cc * 8;
        __syncthreads();
        *(int4*)&ks[(cc * 64 + (rr ^ cc)) * 8]        = *(const int4*)kp;
        *(int4*)&ks[(cc * 64 + ((rr + 32) ^ cc)) * 8] = *(const int4*)(kp + 32 * 512);
        __syncthreads();
        f32x4 sa[4];
#pragma unroll
        for (int i = 0; i < 4; i++) sa[i] = (f32x4){0.f, 0.f, 0.f, 0.f};
#pragma unroll
        for (int j = 0; j < 2; j++) {
            const int cu = j * 4 + fq;
            bf16x8 aq = *(const bf16x8*)&qs[(cu * 64 + ((w * 16 + fm) ^ cu)) * 8];
#pragma unroll
            for (int nb = 0; nb < 4; nb++) {
                bf16x8 bk = *(const bf16x8*)&ks[(cu * 64 + ((nb * 16 + fm) ^ cu)) * 8];
                sa[nb] = __builtin_amdgcn_mfma_f32_16x16x32_bf16(aq, bk, sa[nb], 0, 0, 0);
            }
        }
#pragma unroll
        for (int nb = 0; nb < 4; nb++) {
            const int s_g = s0 + nb * 16 + fm;
#pragma unroll
            for (int r = 0; r < 4; r++) {
                const int t_l = w * 16 + fq * 4 + r;
                const int t_g = tt0 + t_l;
                const float val = (s_g <= t_g) ? sa[nb][r] * inv_s[t_l] : 0.f;
                attb[(size_t)t_g * TDIM + s_g] = val;
            }
        }
    }
    // zero-fill columns right of the diagonal tile
    {
        const float4 z = make_float4(0.f, 0.f, 0.f, 0.f);
        const int r = tid >> 2, qq = tid & 3;
        float* rowp = attb + (size_t)(tt0 + r) * TDIM;
        for (int c0 = (diag + 1) * 64 + qq * 4; c0 < TDIM; c0 += 16)
            *(float4*)(rowp + c0) = z;
    }
}

// ---------------------------------------------------------------------------
extern "C" void kernel_launch(void* const* d_in, const int* in_sizes, int n_in,
                              void* d_out, int out_size, void* d_ws, size_t ws_size,
                              hipStream_t stream) {
    (void)in_sizes; (void)n_in; (void)out_size; (void)ws_size;
    const float* query = (const float*)d_in[0];
    const float* key   = (const float*)d_in[1];
    const float* value = (const float*)d_in[2];
    const float* Wq    = (const float*)d_in[3];
    const float* Wk    = (const float*)d_in[4];
    const float* Wv    = (const float*)d_in[5];
    const float* Wg    = (const float*)d_in[6];
    const float* bg    = (const float*)d_in[7];
    const float* Wo    = (const float*)d_in[8];
    float* out = (float*)d_out;                  // [B,T,M]
    float* att = (float*)d_out + 2097152;        // [B,H,T,T]
    float* ws  = (float*)d_ws;
    float* den  = ws + OFF_DEN;
    float* ksum = ws + OFF_KSUM;
    float* kv   = ws + OFF_KV;
    ushort_t* ub  = (ushort_t*)((char*)d_ws + FLOAT_BYTES);
    ushort_t* qp  = ub + UOFF_QP;
    ushort_t* kp  = ub + UOFF_KP;
    ushort_t* vp  = ub + UOFF_VP;
    ushort_t* nbp = ub + UOFF_NB;
    ushort_t* wqt = ub + UOFF_WQ;
    ushort_t* wkt = ub + UOFF_WK;
    ushort_t* wvt = ub + UOFF_WV;
    ushort_t* wgt = ub + UOFF_WG;
    ushort_t* wot = ub + UOFF_WO;

    dim3 blk(256);
    castwt_all<<<dim3(16, 16, 5), blk, 0, stream>>>(Wq, Wk, Wv, Wg, Wo,
                                                    wqt, wkt, wvt, wgt, wot);
    dim3 ggrid(64, 8);
    mgemm_k<0><<<ggrid, blk, 16384, stream>>>(query, wqt, nullptr, nullptr, qp, nullptr);
    mgemm_k<0><<<ggrid, blk, 16384, stream>>>(key,   wkt, nullptr, nullptr, kp, nullptr);
    mgemm_k<2><<<ggrid, blk, 24576, stream>>>(value, wvt, wgt, bg, vp, nullptr);
    chunksum_k<<<dim3(32, 16), blk, 0, stream>>>(kp, vp, kv, ksum);
    prefix_k<<<dim3(32), blk, 0, stream>>>(kv, ksum);
    chunkout_k<<<dim3(32, 16), blk, 0, stream>>>(qp, kp, vp, kv, ksum, nbp, den);
    attmap_k<<<dim3(32, 16), blk, 0, stream>>>(qp, kp, den, att);
    mgemm_k<1><<<ggrid, blk, 16384, stream>>>(nbp, wot, nullptr, nullptr, nullptr, out);
}

// Round 5
// 266.106 us; speedup vs baseline: 2.0023x; 1.0686x over previous
//
#include <hip/hip_runtime.h>
#include <cstdint>

#define TDIM 1024
#define BDIM 4
#define EPSF 1e-6f

// ---- workspace layout ----
// float region (indices into (float*)d_ws):
#define OFF_DEN   0u          // [32,1024]
#define OFF_KSUM  32768u      // [32,16,64]
#define OFF_KV    65536u      // [32,16,64,64]
#define FLOAT_BYTES 8650752u  // 2,162,688 floats
// ushort (bf16) region (indices into ushort*, after FLOAT_BYTES):
#define UOFF_QP 0u            // q proj bf16 [4096,512]
#define UOFF_KP 2097152u
#define UOFF_VP 4194304u
#define UOFF_NB 6291456u      // normalized numerator bf16 [4096,512]
#define UOFF_WQ 8388608u      // transposed weights [n][k] bf16, 512x512 each
#define UOFF_WK 8650752u
#define UOFF_WV 8912896u
#define UOFF_WG 9175040u
#define UOFF_WO 9437184u

typedef short bf16x8 __attribute__((ext_vector_type(8)));
typedef float f32x4  __attribute__((ext_vector_type(4)));
typedef unsigned short ushort_t;

union bfu { int4 i4; unsigned short us[8]; bf16x8 v; };

__device__ __forceinline__ float phi_f(float x)  { return x > 0.f ? x + 1.f : __expf(x); }
__device__ __forceinline__ float sigm_f(float x) { return 1.f / (1.f + __expf(-x)); }
__device__ __forceinline__ unsigned short f2b(float x) {
    union { float f; unsigned u; } v; v.f = x;
    return (unsigned short)((v.u + 0x7FFFu + ((v.u >> 16) & 1u)) >> 16);
}
__device__ __forceinline__ float b2f(unsigned short s) {
    union { unsigned u; float f; } v; v.u = (unsigned)s << 16; return v.f;
}
__device__ __forceinline__ int4 pack8(float4 a, float4 b) {
    bfu u;
    u.us[0] = f2b(a.x); u.us[1] = f2b(a.y); u.us[2] = f2b(a.z); u.us[3] = f2b(a.w);
    u.us[4] = f2b(b.x); u.us[5] = f2b(b.y); u.us[6] = f2b(b.z); u.us[7] = f2b(b.w);
    return u.i4;
}
#define FMA4(ACC, S, V) do { (ACC).x += (S)*(V).x; (ACC).y += (S)*(V).y; \
                             (ACC).z += (S)*(V).z; (ACC).w += (S)*(V).w; } while (0)

// ---------------------------------------------------------------------------
// cast + transpose all 5 weights: W[512 k][512 n] fp32 -> Wt[512 n][512 k] bf16
// ---------------------------------------------------------------------------
__global__ __launch_bounds__(256) void castwt_all(const float* __restrict__ W0,
                                                  const float* __restrict__ W1,
                                                  const float* __restrict__ W2,
                                                  const float* __restrict__ W3,
                                                  const float* __restrict__ W4,
                                                  ushort_t* __restrict__ T0,
                                                  ushort_t* __restrict__ T1,
                                                  ushort_t* __restrict__ T2,
                                                  ushort_t* __restrict__ T3,
                                                  ushort_t* __restrict__ T4) {
    const float* W; ushort_t* Wt;
    switch (blockIdx.z) {
        case 0: W = W0; Wt = T0; break;
        case 1: W = W1; Wt = T1; break;
        case 2: W = W2; Wt = T2; break;
        case 3: W = W3; Wt = T3; break;
        default: W = W4; Wt = T4; break;
    }
    __shared__ unsigned short tile[32][36];
    const int t = threadIdx.x;
    const int r0 = blockIdx.y * 32, c0 = blockIdx.x * 32;
    {
        const int r = t >> 3, c4 = (t & 7) * 4;
        float4 x = *(const float4*)(W + (size_t)(r0 + r) * 512 + c0 + c4);
        tile[c4 + 0][r] = f2b(x.x); tile[c4 + 1][r] = f2b(x.y);
        tile[c4 + 2][r] = f2b(x.z); tile[c4 + 3][r] = f2b(x.w);
    }
    __syncthreads();
    const int c = t >> 3, r4 = (t & 7) * 4;
    ushort4 o;
    o.x = tile[c][r4 + 0]; o.y = tile[c][r4 + 1];
    o.z = tile[c][r4 + 2]; o.w = tile[c][r4 + 3];
    *(ushort4*)(Wt + (size_t)(c0 + c) * 512 + r0 + r4) = o;
}

// ---------------------------------------------------------------------------
// Fused projection GEMM, grid (64,8,3), double-buffered K-loop (1 barrier/iter)
//   z=0: phi(query@Wq) -> qp     z=1: phi(key@Wk) -> kp
//   z=2: (value@Wv) * 2*sigmoid(value@Wg + bg) -> vp
// 64x64 tile, BK=64, 4 waves. LDS frag-ordered + XOR swizzle.
// ---------------------------------------------------------------------------
__global__ __launch_bounds__(256) void proj_k(const float* __restrict__ query,
                                              const float* __restrict__ key_,
                                              const float* __restrict__ value,
                                              const ushort_t* __restrict__ wqt,
                                              const ushort_t* __restrict__ wkt,
                                              const ushort_t* __restrict__ wvt,
                                              const ushort_t* __restrict__ wgt,
                                              const float* __restrict__ bg,
                                              ushort_t* __restrict__ qp,
                                              ushort_t* __restrict__ kp,
                                              ushort_t* __restrict__ vp) {
    __shared__ __align__(16) unsigned short As[2][4096];
    __shared__ __align__(16) unsigned short Bs[2][4096];
    __shared__ __align__(16) unsigned short Bs2[2][4096];
    const int z = blockIdx.z;
    const float* A = (z == 0) ? query : (z == 1) ? key_ : value;
    const ushort_t* B0 = (z == 0) ? wqt : (z == 1) ? wkt : wvt;
    ushort_t* outp = (z == 0) ? qp : (z == 1) ? kp : vp;
    const bool dual = (z == 2);

    const int tid = threadIdx.x;
    const int row0 = blockIdx.x * 64, n0 = blockIdx.y * 64;
    const int w = tid >> 6, lane = tid & 63;
    const int cc = tid & 7, rr = tid >> 3;
    const int fm = lane & 15, fq = lane >> 4;
    const int la0 = (cc * 64 + (rr ^ cc)) * 8;
    const int la1 = (cc * 64 + ((rr + 32) ^ cc)) * 8;

    f32x4 acc[4], acc2[4];
#pragma unroll
    for (int i = 0; i < 4; i++) {
        acc[i]  = (f32x4){0.f, 0.f, 0.f, 0.f};
        acc2[i] = (f32x4){0.f, 0.f, 0.f, 0.f};
    }

    const float*   aptr = A  + (size_t)(row0 + rr) * 512 + cc * 8;
    const ushort_t* bptr = B0 + (size_t)(n0 + rr) * 512 + cc * 8;
    const ushort_t* gptr = wgt + (size_t)(n0 + rr) * 512 + cc * 8;

    float4 a0 = *(const float4*)(aptr);
    float4 a1 = *(const float4*)(aptr + 4);
    float4 a2 = *(const float4*)(aptr + 32 * 512);
    float4 a3 = *(const float4*)(aptr + 32 * 512 + 4);
    int4 b0 = *(const int4*)(bptr);
    int4 b1 = *(const int4*)(bptr + 32 * 512);
    int4 g0 = {0, 0, 0, 0}, g1 = {0, 0, 0, 0};
    if (dual) { g0 = *(const int4*)(gptr); g1 = *(const int4*)(gptr + 32 * 512); }
    *(int4*)&As[0][la0] = pack8(a0, a1);
    *(int4*)&As[0][la1] = pack8(a2, a3);
    *(int4*)&Bs[0][la0] = b0; *(int4*)&Bs[0][la1] = b1;
    if (dual) { *(int4*)&Bs2[0][la0] = g0; *(int4*)&Bs2[0][la1] = g1; }
    __syncthreads();

    for (int kti = 0; kti < 8; kti++) {
        const int buf = kti & 1;
        if (kti < 7) {
            const int off = (kti + 1) * 64;
            a0 = *(const float4*)(aptr + off);
            a1 = *(const float4*)(aptr + off + 4);
            a2 = *(const float4*)(aptr + off + 32 * 512);
            a3 = *(const float4*)(aptr + off + 32 * 512 + 4);
            b0 = *(const int4*)(bptr + off);
            b1 = *(const int4*)(bptr + off + 32 * 512);
            if (dual) {
                g0 = *(const int4*)(gptr + off);
                g1 = *(const int4*)(gptr + off + 32 * 512);
            }
        }
        if (dual) {
#pragma unroll
            for (int j = 0; j < 2; j++) {
                const int cu = j * 4 + fq;
                bf16x8 af = *(const bf16x8*)&As[buf][(cu * 64 + ((w * 16 + fm) ^ cu)) * 8];
#pragma unroll
                for (int nb = 0; nb < 4; nb++) {
                    bf16x8 bv = *(const bf16x8*)&Bs[buf][(cu * 64 + ((nb * 16 + fm) ^ cu)) * 8];
                    bf16x8 gv = *(const bf16x8*)&Bs2[buf][(cu * 64 + ((nb * 16 + fm) ^ cu)) * 8];
                    acc[nb]  = __builtin_amdgcn_mfma_f32_16x16x32_bf16(af, bv, acc[nb], 0, 0, 0);
                    acc2[nb] = __builtin_amdgcn_mfma_f32_16x16x32_bf16(af, gv, acc2[nb], 0, 0, 0);
                }
            }
        } else {
#pragma unroll
            for (int j = 0; j < 2; j++) {
                const int cu = j * 4 + fq;
                bf16x8 af = *(const bf16x8*)&As[buf][(cu * 64 + ((w * 16 + fm) ^ cu)) * 8];
#pragma unroll
                for (int nb = 0; nb < 4; nb++) {
                    bf16x8 bv = *(const bf16x8*)&Bs[buf][(cu * 64 + ((nb * 16 + fm) ^ cu)) * 8];
                    acc[nb] = __builtin_amdgcn_mfma_f32_16x16x32_bf16(af, bv, acc[nb], 0, 0, 0);
                }
            }
        }
        if (kti < 7) {
            const int nb_ = buf ^ 1;
            *(int4*)&As[nb_][la0] = pack8(a0, a1);
            *(int4*)&As[nb_][la1] = pack8(a2, a3);
            *(int4*)&Bs[nb_][la0] = b0; *(int4*)&Bs[nb_][la1] = b1;
            if (dual) { *(int4*)&Bs2[nb_][la0] = g0; *(int4*)&Bs2[nb_][la1] = g1; }
            __syncthreads();
        }
    }

#pragma unroll
    for (int nb = 0; nb < 4; nb++) {
        const int col = n0 + nb * 16 + fm;
        const float bb = dual ? bg[col] : 0.f;
#pragma unroll
        for (int r = 0; r < 4; r++) {
            const int row = row0 + w * 16 + fq * 4 + r;
            const float v = acc[nb][r];
            const ushort_t o = dual ? f2b(v * 2.f * sigm_f(acc2[nb][r] + bb))
                                    : f2b(phi_f(v));
            outp[(size_t)row * 512 + col] = o;
        }
    }
}

// ---------------------------------------------------------------------------
// Output projection: out[4096,512] fp32 = nb(bf16) @ Wo^T, double-buffered
// ---------------------------------------------------------------------------
__global__ __launch_bounds__(256) void outproj_k(const ushort_t* __restrict__ A,
                                                 const ushort_t* __restrict__ Bt,
                                                 float* __restrict__ out) {
    __shared__ __align__(16) unsigned short As[2][4096];
    __shared__ __align__(16) unsigned short Bs[2][4096];
    const int tid = threadIdx.x;
    const int row0 = blockIdx.x * 64, n0 = blockIdx.y * 64;
    const int w = tid >> 6, lane = tid & 63;
    const int cc = tid & 7, rr = tid >> 3;
    const int fm = lane & 15, fq = lane >> 4;
    const int la0 = (cc * 64 + (rr ^ cc)) * 8;
    const int la1 = (cc * 64 + ((rr + 32) ^ cc)) * 8;

    f32x4 acc[4];
#pragma unroll
    for (int i = 0; i < 4; i++) acc[i] = (f32x4){0.f, 0.f, 0.f, 0.f};

    const ushort_t* aptr = A  + (size_t)(row0 + rr) * 512 + cc * 8;
    const ushort_t* bptr = Bt + (size_t)(n0 + rr) * 512 + cc * 8;
    int4 ra0 = *(const int4*)(aptr);
    int4 ra1 = *(const int4*)(aptr + 32 * 512);
    int4 rb0 = *(const int4*)(bptr);
    int4 rb1 = *(const int4*)(bptr + 32 * 512);
    *(int4*)&As[0][la0] = ra0; *(int4*)&As[0][la1] = ra1;
    *(int4*)&Bs[0][la0] = rb0; *(int4*)&Bs[0][la1] = rb1;
    __syncthreads();

    for (int kti = 0; kti < 8; kti++) {
        const int buf = kti & 1;
        if (kti < 7) {
            const int off = (kti + 1) * 64;
            ra0 = *(const int4*)(aptr + off);
            ra1 = *(const int4*)(aptr + off + 32 * 512);
            rb0 = *(const int4*)(bptr + off);
            rb1 = *(const int4*)(bptr + off + 32 * 512);
        }
#pragma unroll
        for (int j = 0; j < 2; j++) {
            const int cu = j * 4 + fq;
            bf16x8 af = *(const bf16x8*)&As[buf][(cu * 64 + ((w * 16 + fm) ^ cu)) * 8];
#pragma unroll
            for (int nb = 0; nb < 4; nb++) {
                bf16x8 bv = *(const bf16x8*)&Bs[buf][(cu * 64 + ((nb * 16 + fm) ^ cu)) * 8];
                acc[nb] = __builtin_amdgcn_mfma_f32_16x16x32_bf16(af, bv, acc[nb], 0, 0, 0);
            }
        }
        if (kti < 7) {
            const int nb_ = buf ^ 1;
            *(int4*)&As[nb_][la0] = ra0; *(int4*)&As[nb_][la1] = ra1;
            *(int4*)&Bs[nb_][la0] = rb0; *(int4*)&Bs[nb_][la1] = rb1;
            __syncthreads();
        }
    }
#pragma unroll
    for (int nb = 0; nb < 4; nb++) {
        const int col = n0 + nb * 16 + fm;
#pragma unroll
        for (int r = 0; r < 4; r++) {
            const int row = row0 + w * 16 + fq * 4 + r;
            __builtin_nontemporal_store(acc[nb][r], &out[(size_t)row * 512 + col]);
        }
    }
}

// ---------------------------------------------------------------------------
// K2a: per-(b,h,chunk) sums from bf16 projections
// ---------------------------------------------------------------------------
__global__ __launch_bounds__(256) void chunksum_k(const ushort_t* __restrict__ kb,
                                                  const ushort_t* __restrict__ vb,
                                                  float* __restrict__ kv,
                                                  float* __restrict__ ksum) {
    __shared__ __align__(16) float kf_c[64][68];
    __shared__ __align__(16) float vg_c[64][68];
    const int tid = threadIdx.x;
    const int bh = blockIdx.x, c = blockIdx.y;
    const int b = bh >> 3, h = bh & 7;
    const int r = tid >> 2, qq = tid & 3;
    {
        const size_t rowbase = ((size_t)(b * TDIM + c * 64 + r)) * 512 + h * 64 + qq * 16;
        bfu k0, k1, v0, v1;
        k0.i4 = *(const int4*)(kb + rowbase);
        k1.i4 = *(const int4*)(kb + rowbase + 8);
        v0.i4 = *(const int4*)(vb + rowbase);
        v1.i4 = *(const int4*)(vb + rowbase + 8);
#pragma unroll
        for (int j = 0; j < 8; j++) {
            kf_c[r][qq * 16 + j]     = b2f(k0.us[j]);
            kf_c[r][qq * 16 + 8 + j] = b2f(k1.us[j]);
            vg_c[r][qq * 16 + j]     = b2f(v0.us[j]);
            vg_c[r][qq * 16 + 8 + j] = b2f(v1.us[j]);
        }
    }
    __syncthreads();
    const int k0i = (tid >> 4) * 4;
    const int v0i = (tid & 15) * 4;
    float4 a4[4];
#pragma unroll
    for (int i = 0; i < 4; i++) a4[i] = make_float4(0.f, 0.f, 0.f, 0.f);
    for (int t = 0; t < 64; t++) {
        float4 kk4 = *(const float4*)&kf_c[t][k0i];
        float4 vv  = *(const float4*)&vg_c[t][v0i];
        FMA4(a4[0], kk4.x, vv); FMA4(a4[1], kk4.y, vv);
        FMA4(a4[2], kk4.z, vv); FMA4(a4[3], kk4.w, vv);
    }
    const size_t base = (size_t)(bh * 16 + c) * 64;
#pragma unroll
    for (int i = 0; i < 4; i++)
        *(float4*)(kv + (base + k0i + i) * 64 + v0i) = a4[i];
    if (tid < 64) {
        float s = 0.f;
        for (int t = 0; t < 64; t++) s += kf_c[t][tid];
        ksum[base + tid] = s;
    }
}

// ---------------------------------------------------------------------------
// K2b: in-place exclusive prefix over the 16 chunks (per bh)
// ---------------------------------------------------------------------------
__global__ __launch_bounds__(256) void prefix_k(float* __restrict__ kv,
                                                float* __restrict__ ksum) {
    const int tid = threadIdx.x;
    const int bh = blockIdx.x;
    float4 run[4];
#pragma unroll
    for (int u = 0; u < 4; u++) run[u] = make_float4(0.f, 0.f, 0.f, 0.f);
    const int d0 = tid * 16;
    for (int c = 0; c < 16; c++) {
        float* p = kv + (size_t)(bh * 16 + c) * 4096 + d0;
#pragma unroll
        for (int u = 0; u < 4; u++) {
            float4 x = *(float4*)(p + 4 * u);
            *(float4*)(p + 4 * u) = run[u];
            run[u].x += x.x; run[u].y += x.y; run[u].z += x.z; run[u].w += x.w;
        }
    }
    if (tid < 64) {
        float r2 = 0.f;
        for (int c = 0; c < 16; c++) {
            float* p = ksum + (size_t)(bh * 16 + c) * 64 + tid;
            float x = *p; *p = r2; r2 += x;
        }
    }
}

// ---------------------------------------------------------------------------
// K2c (MFMA): per-(b,h,chunk) diag tile: S, denom, normalized numerator
// ---------------------------------------------------------------------------
__global__ __launch_bounds__(256) void chunkout_k(const ushort_t* __restrict__ qb,
                                                  const ushort_t* __restrict__ kb,
                                                  const ushort_t* __restrict__ vb,
                                                  const float* __restrict__ kvp,
                                                  const float* __restrict__ ksum,
                                                  ushort_t* __restrict__ nbo,
                                                  float* __restrict__ denom) {
    __shared__ __align__(16) unsigned short qs[4096];
    __shared__ __align__(16) unsigned short ks[4096];
    __shared__ __align__(16) unsigned short vs[4096];   // V^T frag-ordered
    __shared__ __align__(16) unsigned short kvs[4096];  // KVpre^T frag-ordered
    __shared__ __align__(16) float sc[64][68];
    __shared__ __align__(16) float kpre[64];
    __shared__ __align__(16) float ps[64][4];
    __shared__ __align__(16) float inv_s[64];
    const int tid = threadIdx.x;
    const int bh = blockIdx.x, c = blockIdx.y;
    const int b = bh >> 3, h = bh & 7;
    const int w = tid >> 6, lane = tid & 63;
    const int fm = lane & 15, fq = lane >> 4;

    // phase 0: staging
    {
        const int rr = tid >> 3, cc = tid & 7;
        const ushort_t* qp = qb + ((size_t)(b * TDIM + c * 64 + rr)) * 512 + h * 64 + cc * 8;
        const ushort_t* kp = kb + ((size_t)(b * TDIM + c * 64 + rr)) * 512 + h * 64 + cc * 8;
        *(int4*)&qs[(cc * 64 + (rr ^ cc)) * 8]        = *(const int4*)qp;
        *(int4*)&qs[(cc * 64 + ((rr + 32) ^ cc)) * 8] = *(const int4*)(qp + 32 * 512);
        *(int4*)&ks[(cc * 64 + (rr ^ cc)) * 8]        = *(const int4*)kp;
        *(int4*)&ks[(cc * 64 + ((rr + 32) ^ cc)) * 8] = *(const int4*)(kp + 32 * 512);
        const int v = tid & 63, su0 = (tid >> 6) * 2;
#pragma unroll
        for (int e = 0; e < 2; e++) {
            const int su = su0 + e;
            bfu t1;
#pragma unroll
            for (int j = 0; j < 8; j++)
                t1.us[j] = vb[((size_t)(b * TDIM + c * 64 + su * 8 + j)) * 512 + h * 64 + v];
            *(int4*)&vs[(su * 64 + (v ^ su)) * 8] = t1.i4;
            bfu t2;
            const float* kvrow = kvp + (size_t)(bh * 16 + c) * 4096 + v;
#pragma unroll
            for (int j = 0; j < 8; j++)
                t2.us[j] = f2b(kvrow[(su * 8 + j) * 64]);
            *(int4*)&kvs[(su * 64 + (v ^ su)) * 8] = t2.i4;
        }
        if (tid < 64) kpre[tid] = ksum[(size_t)(bh * 16 + c) * 64 + tid];
    }
    __syncthreads();

    // phase 1: S = Q.K^T, mask, -> sc
    {
        f32x4 sa[4];
#pragma unroll
        for (int i = 0; i < 4; i++) sa[i] = (f32x4){0.f, 0.f, 0.f, 0.f};
#pragma unroll
        for (int j = 0; j < 2; j++) {
            const int cu = j * 4 + fq;
            bf16x8 aq = *(const bf16x8*)&qs[(cu * 64 + ((w * 16 + fm) ^ cu)) * 8];
#pragma unroll
            for (int nb = 0; nb < 4; nb++) {
                bf16x8 bk = *(const bf16x8*)&ks[(cu * 64 + ((nb * 16 + fm) ^ cu)) * 8];
                sa[nb] = __builtin_amdgcn_mfma_f32_16x16x32_bf16(aq, bk, sa[nb], 0, 0, 0);
            }
        }
#pragma unroll
        for (int nb = 0; nb < 4; nb++) {
            const int s_l = nb * 16 + fm;
#pragma unroll
            for (int r = 0; r < 4; r++) {
                const int t_l = w * 16 + fq * 4 + r;
                sc[t_l][s_l] = (s_l <= t_l) ? sa[nb][r] : 0.f;
            }
        }
    }
    __syncthreads();

    // phase 2: denom
    {
        const int rw = tid >> 2, sq = tid & 3;
        float p = 0.f;
#pragma unroll
        for (int s = sq * 16; s < sq * 16 + 16; s++) p += sc[rw][s];
#pragma unroll
        for (int kd = sq * 16; kd < sq * 16 + 16; kd++) {
            const int cu = kd >> 3;
            p += b2f(qs[(cu * 64 + (rw ^ cu)) * 8 + (kd & 7)]) * kpre[kd];
        }
        ps[rw][sq] = p;
    }
    __syncthreads();
    {
        const int rw = tid >> 2, sq = tid & 3;
        if (sq == 0) {
            float den = ps[rw][0] + ps[rw][1] + ps[rw][2] + ps[rw][3];
            denom[(size_t)bh * TDIM + c * 64 + rw] = den;
            inv_s[rw] = 1.f / (den + EPSF);
        }
    }
    __syncthreads();

    // phase 3: numer = Q.KVpre^T + P.V^T, scaled by inv
    {
        f32x4 oa[4];
#pragma unroll
        for (int i = 0; i < 4; i++) oa[i] = (f32x4){0.f, 0.f, 0.f, 0.f};
        bf16x8 aq[2], ap_[2];
#pragma unroll
        for (int j = 0; j < 2; j++) {
            const int cu = j * 4 + fq;
            aq[j] = *(const bf16x8*)&qs[(cu * 64 + ((w * 16 + fm) ^ cu)) * 8];
            bfu t;
#pragma unroll
            for (int e2 = 0; e2 < 8; e2++) t.us[e2] = f2b(sc[w * 16 + fm][cu * 8 + e2]);
            ap_[j] = t.v;
        }
#pragma unroll
        for (int nb = 0; nb < 4; nb++) {
#pragma unroll
            for (int j = 0; j < 2; j++) {
                const int cu = j * 4 + fq;
                bf16x8 bkv = *(const bf16x8*)&kvs[(cu * 64 + ((nb * 16 + fm) ^ cu)) * 8];
                bf16x8 bv  = *(const bf16x8*)&vs[(cu * 64 + ((nb * 16 + fm) ^ cu)) * 8];
                oa[nb] = __builtin_amdgcn_mfma_f32_16x16x32_bf16(aq[j], bkv, oa[nb], 0, 0, 0);
                oa[nb] = __builtin_amdgcn_mfma_f32_16x16x32_bf16(ap_[j], bv, oa[nb], 0, 0, 0);
            }
        }
#pragma unroll
        for (int nb = 0; nb < 4; nb++) {
            const int vcol = nb * 16 + fm;
#pragma unroll
            for (int r = 0; r < 4; r++) {
                const int t_l = w * 16 + fq * 4 + r;
                const float val = oa[nb][r] * inv_s[t_l];
                nbo[((size_t)(b * TDIM + c * 64 + t_l)) * 512 + h * 64 + vcol] = f2b(val);
            }
        }
    }
}

// ---------------------------------------------------------------------------
// K3 (MFMA): att_map tiles, double-buffered K staging (1 barrier/tile),
// q-frags in registers, nontemporal stores.
// ---------------------------------------------------------------------------
__global__ __launch_bounds__(256) void attmap_k(const ushort_t* __restrict__ qb,
                                                const ushort_t* __restrict__ kb,
                                                const float* __restrict__ denom,
                                                float* __restrict__ att) {
    __shared__ __align__(16) unsigned short qs[4096];
    __shared__ __align__(16) unsigned short ks[2][4096];
    __shared__ __align__(16) float inv_s[64];
    const int tid = threadIdx.x;
    const int bh = blockIdx.x, diag = blockIdx.y;
    const int tt0 = diag * 64;
    const int b = bh >> 3, h = bh & 7;
    const int w = tid >> 6, lane = tid & 63;
    const int fm = lane & 15, fq = lane >> 4;
    const int rr = tid >> 3, cc = tid & 7;
    const int la0 = (cc * 64 + (rr ^ cc)) * 8;
    const int la1 = (cc * 64 + ((rr + 32) ^ cc)) * 8;

    const ushort_t* qptr = qb + ((size_t)(b * TDIM + tt0 + rr)) * 512 + h * 64 + cc * 8;
    const ushort_t* kbase = kb + ((size_t)(b * TDIM + rr)) * 512 + h * 64 + cc * 8;
    *(int4*)&qs[la0] = *(const int4*)qptr;
    *(int4*)&qs[la1] = *(const int4*)(qptr + 32 * 512);
    int4 rk0 = *(const int4*)(kbase);
    int4 rk1 = *(const int4*)(kbase + 32 * 512);
    *(int4*)&ks[0][la0] = rk0;
    *(int4*)&ks[0][la1] = rk1;
    if (tid < 64) inv_s[tid] = 1.f / (denom[(size_t)bh * TDIM + tt0 + tid] + EPSF);
    __syncthreads();

    bf16x8 aq[2];
    float invr[4];
#pragma unroll
    for (int j = 0; j < 2; j++) {
        const int cu = j * 4 + fq;
        aq[j] = *(const bf16x8*)&qs[(cu * 64 + ((w * 16 + fm) ^ cu)) * 8];
    }
#pragma unroll
    for (int r = 0; r < 4; r++) invr[r] = inv_s[w * 16 + fq * 4 + r];

    float* attb = att + (size_t)bh * TDIM * TDIM;
    for (int st = 0; st <= diag; st++) {
        const int buf = st & 1;
        if (st < diag) {
            const size_t off = (size_t)(st + 1) * 64 * 512;
            rk0 = *(const int4*)(kbase + off);
            rk1 = *(const int4*)(kbase + off + 32 * 512);
        }
        f32x4 sa[4];
#pragma unroll
        for (int i = 0; i < 4; i++) sa[i] = (f32x4){0.f, 0.f, 0.f, 0.f};
#pragma unroll
        for (int j = 0; j < 2; j++) {
            const int cu = j * 4 + fq;
#pragma unroll
            for (int nb = 0; nb < 4; nb++) {
                bf16x8 bk = *(const bf16x8*)&ks[buf][(cu * 64 + ((nb * 16 + fm) ^ cu)) * 8];
                sa[nb] = __builtin_amdgcn_mfma_f32_16x16x32_bf16(aq[j], bk, sa[nb], 0, 0, 0);
            }
        }
        const int s0 = st * 64;
        if (st < diag) {
            // fully below diagonal: no mask needed
#pragma unroll
            for (int nb = 0; nb < 4; nb++) {
                const int s_g = s0 + nb * 16 + fm;
#pragma unroll
                for (int r = 0; r < 4; r++) {
                    const int t_g = tt0 + w * 16 + fq * 4 + r;
                    __builtin_nontemporal_store(sa[nb][r] * invr[r],
                                                &attb[(size_t)t_g * TDIM + s_g]);
                }
            }
            *(int4*)&ks[buf ^ 1][la0] = rk0;
            *(int4*)&ks[buf ^ 1][la1] = rk1;
            __syncthreads();
        } else {
            // diagonal tile: causal mask
#pragma unroll
            for (int nb = 0; nb < 4; nb++) {
                const int s_l = nb * 16 + fm;
#pragma unroll
                for (int r = 0; r < 4; r++) {
                    const int t_l = w * 16 + fq * 4 + r;
                    const float val = (s_l <= t_l) ? sa[nb][r] * invr[r] : 0.f;
                    __builtin_nontemporal_store(val,
                        &attb[(size_t)(tt0 + t_l) * TDIM + s0 + s_l]);
                }
            }
        }
    }
    // zero-fill columns right of the diagonal tile
    {
        const f32x4 z = (f32x4){0.f, 0.f, 0.f, 0.f};
        const int r = tid >> 2, qq = tid & 3;
        float* rowp = attb + (size_t)(tt0 + r) * TDIM;
        for (int c0 = (diag + 1) * 64 + qq * 4; c0 < TDIM; c0 += 16)
            __builtin_nontemporal_store(z, (f32x4*)(rowp + c0));
    }
}

// ---------------------------------------------------------------------------
extern "C" void kernel_launch(void* const* d_in, const int* in_sizes, int n_in,
                              void* d_out, int out_size, void* d_ws, size_t ws_size,
                              hipStream_t stream) {
    (void)in_sizes; (void)n_in; (void)out_size; (void)ws_size;
    const float* query = (const float*)d_in[0];
    const float* key   = (const float*)d_in[1];
    const float* value = (const float*)d_in[2];
    const float* Wq    = (const float*)d_in[3];
    const float* Wk    = (const float*)d_in[4];
    const float* Wv    = (const float*)d_in[5];
    const float* Wg    = (const float*)d_in[6];
    const float* bg    = (const float*)d_in[7];
    const float* Wo    = (const float*)d_in[8];
    float* out = (float*)d_out;                  // [B,T,M]
    float* att = (float*)d_out + 2097152;        // [B,H,T,T]
    float* ws  = (float*)d_ws;
    float* den  = ws + OFF_DEN;
    float* ksum = ws + OFF_KSUM;
    float* kv   = ws + OFF_KV;
    ushort_t* ub  = (ushort_t*)((char*)d_ws + FLOAT_BYTES);
    ushort_t* qp  = ub + UOFF_QP;
    ushort_t* kp  = ub + UOFF_KP;
    ushort_t* vp  = ub + UOFF_VP;
    ushort_t* nbp = ub + UOFF_NB;
    ushort_t* wqt = ub + UOFF_WQ;
    ushort_t* wkt = ub + UOFF_WK;
    ushort_t* wvt = ub + UOFF_WV;
    ushort_t* wgt = ub + UOFF_WG;
    ushort_t* wot = ub + UOFF_WO;

    dim3 blk(256);
    castwt_all<<<dim3(16, 16, 5), blk, 0, stream>>>(Wq, Wk, Wv, Wg, Wo,
                                                    wqt, wkt, wvt, wgt, wot);
    proj_k<<<dim3(64, 8, 3), blk, 0, stream>>>(query, key, value,
                                               wqt, wkt, wvt, wgt, bg, qp, kp, vp);
    chunksum_k<<<dim3(32, 16), blk, 0, stream>>>(kp, vp, kv, ksum);
    prefix_k<<<dim3(32), blk, 0, stream>>>(kv, ksum);
    chunkout_k<<<dim3(32, 16), blk, 0, stream>>>(qp, kp, vp, kv, ksum, nbp, den);
    attmap_k<<<dim3(32, 16), blk, 0, stream>>>(qp, kp, den, att);
    outproj_k<<<dim3(64, 8), blk, 0, stream>>>(nbp, wot, out);
}

// Round 6
// 244.993 us; speedup vs baseline: 2.1748x; 1.0862x over previous
//
#include <hip/hip_runtime.h>
#include <cstdint>

#define TDIM 1024
#define BDIM 4
#define EPSF 1e-6f

// ---- workspace layout ----
// float region (indices into (float*)d_ws):
#define OFF_KSUM  32768u      // [32,16,64]   raw per-chunk k sums
#define OFF_KV    65536u      // [32,16,64,64] raw per-chunk kv sums
#define FLOAT_BYTES 8650752u  // 2,162,688 floats
// ushort (bf16) region (indices into ushort*, after FLOAT_BYTES):
#define UOFF_QP 0u            // q proj bf16 [4096,512]
#define UOFF_KP 2097152u
#define UOFF_VP 4194304u
#define UOFF_NB 6291456u      // normalized numerator bf16 [4096,512]
#define UOFF_WQ 8388608u      // transposed weights [n][k] bf16, 512x512 each
#define UOFF_WK 8650752u
#define UOFF_WV 8912896u
#define UOFF_WG 9175040u
#define UOFF_WO 9437184u

typedef short bf16x8 __attribute__((ext_vector_type(8)));
typedef float f32x4  __attribute__((ext_vector_type(4)));
typedef unsigned short ushort_t;

union bfu { int4 i4; unsigned short us[8]; bf16x8 v; };

__device__ __forceinline__ float phi_f(float x)  { return x > 0.f ? x + 1.f : __expf(x); }
__device__ __forceinline__ float sigm_f(float x) { return 1.f / (1.f + __expf(-x)); }
__device__ __forceinline__ unsigned short f2b(float x) {
    union { float f; unsigned u; } v; v.f = x;
    return (unsigned short)((v.u + 0x7FFFu + ((v.u >> 16) & 1u)) >> 16);
}
__device__ __forceinline__ float b2f(unsigned short s) {
    union { unsigned u; float f; } v; v.u = (unsigned)s << 16; return v.f;
}
__device__ __forceinline__ int4 pack8(float4 a, float4 b) {
    bfu u;
    u.us[0] = f2b(a.x); u.us[1] = f2b(a.y); u.us[2] = f2b(a.z); u.us[3] = f2b(a.w);
    u.us[4] = f2b(b.x); u.us[5] = f2b(b.y); u.us[6] = f2b(b.z); u.us[7] = f2b(b.w);
    return u.i4;
}
#define FMA4(ACC, S, V) do { (ACC).x += (S)*(V).x; (ACC).y += (S)*(V).y; \
                             (ACC).z += (S)*(V).z; (ACC).w += (S)*(V).w; } while (0)

// ---------------------------------------------------------------------------
// cast + transpose all 5 weights: W[512 k][512 n] fp32 -> Wt[512 n][512 k] bf16
// ---------------------------------------------------------------------------
__global__ __launch_bounds__(256) void castwt_all(const float* __restrict__ W0,
                                                  const float* __restrict__ W1,
                                                  const float* __restrict__ W2,
                                                  const float* __restrict__ W3,
                                                  const float* __restrict__ W4,
                                                  ushort_t* __restrict__ T0,
                                                  ushort_t* __restrict__ T1,
                                                  ushort_t* __restrict__ T2,
                                                  ushort_t* __restrict__ T3,
                                                  ushort_t* __restrict__ T4) {
    const float* W; ushort_t* Wt;
    switch (blockIdx.z) {
        case 0: W = W0; Wt = T0; break;
        case 1: W = W1; Wt = T1; break;
        case 2: W = W2; Wt = T2; break;
        case 3: W = W3; Wt = T3; break;
        default: W = W4; Wt = T4; break;
    }
    __shared__ unsigned short tile[32][36];
    const int t = threadIdx.x;
    const int r0 = blockIdx.y * 32, c0 = blockIdx.x * 32;
    {
        const int r = t >> 3, c4 = (t & 7) * 4;
        float4 x = *(const float4*)(W + (size_t)(r0 + r) * 512 + c0 + c4);
        tile[c4 + 0][r] = f2b(x.x); tile[c4 + 1][r] = f2b(x.y);
        tile[c4 + 2][r] = f2b(x.z); tile[c4 + 3][r] = f2b(x.w);
    }
    __syncthreads();
    const int c = t >> 3, r4 = (t & 7) * 4;
    ushort4 o;
    o.x = tile[c][r4 + 0]; o.y = tile[c][r4 + 1];
    o.z = tile[c][r4 + 2]; o.w = tile[c][r4 + 3];
    *(ushort4*)(Wt + (size_t)(c0 + c) * 512 + r0 + r4) = o;
}

// ---------------------------------------------------------------------------
// Fused projection GEMM, grid (64,8,3), double-buffered K-loop
// ---------------------------------------------------------------------------
__global__ __launch_bounds__(256) void proj_k(const float* __restrict__ query,
                                              const float* __restrict__ key_,
                                              const float* __restrict__ value,
                                              const ushort_t* __restrict__ wqt,
                                              const ushort_t* __restrict__ wkt,
                                              const ushort_t* __restrict__ wvt,
                                              const ushort_t* __restrict__ wgt,
                                              const float* __restrict__ bg,
                                              ushort_t* __restrict__ qp,
                                              ushort_t* __restrict__ kp,
                                              ushort_t* __restrict__ vp) {
    __shared__ __align__(16) unsigned short As[2][4096];
    __shared__ __align__(16) unsigned short Bs[2][4096];
    __shared__ __align__(16) unsigned short Bs2[2][4096];
    const int z = blockIdx.z;
    const float* A = (z == 0) ? query : (z == 1) ? key_ : value;
    const ushort_t* B0 = (z == 0) ? wqt : (z == 1) ? wkt : wvt;
    ushort_t* outp = (z == 0) ? qp : (z == 1) ? kp : vp;
    const bool dual = (z == 2);

    const int tid = threadIdx.x;
    const int row0 = blockIdx.x * 64, n0 = blockIdx.y * 64;
    const int w = tid >> 6, lane = tid & 63;
    const int cc = tid & 7, rr = tid >> 3;
    const int fm = lane & 15, fq = lane >> 4;
    const int la0 = (cc * 64 + (rr ^ cc)) * 8;
    const int la1 = (cc * 64 + ((rr + 32) ^ cc)) * 8;

    f32x4 acc[4], acc2[4];
#pragma unroll
    for (int i = 0; i < 4; i++) {
        acc[i]  = (f32x4){0.f, 0.f, 0.f, 0.f};
        acc2[i] = (f32x4){0.f, 0.f, 0.f, 0.f};
    }

    const float*   aptr = A  + (size_t)(row0 + rr) * 512 + cc * 8;
    const ushort_t* bptr = B0 + (size_t)(n0 + rr) * 512 + cc * 8;
    const ushort_t* gptr = wgt + (size_t)(n0 + rr) * 512 + cc * 8;

    float4 a0 = *(const float4*)(aptr);
    float4 a1 = *(const float4*)(aptr + 4);
    float4 a2 = *(const float4*)(aptr + 32 * 512);
    float4 a3 = *(const float4*)(aptr + 32 * 512 + 4);
    int4 b0 = *(const int4*)(bptr);
    int4 b1 = *(const int4*)(bptr + 32 * 512);
    int4 g0 = {0, 0, 0, 0}, g1 = {0, 0, 0, 0};
    if (dual) { g0 = *(const int4*)(gptr); g1 = *(const int4*)(gptr + 32 * 512); }
    *(int4*)&As[0][la0] = pack8(a0, a1);
    *(int4*)&As[0][la1] = pack8(a2, a3);
    *(int4*)&Bs[0][la0] = b0; *(int4*)&Bs[0][la1] = b1;
    if (dual) { *(int4*)&Bs2[0][la0] = g0; *(int4*)&Bs2[0][la1] = g1; }
    __syncthreads();

    for (int kti = 0; kti < 8; kti++) {
        const int buf = kti & 1;
        if (kti < 7) {
            const int off = (kti + 1) * 64;
            a0 = *(const float4*)(aptr + off);
            a1 = *(const float4*)(aptr + off + 4);
            a2 = *(const float4*)(aptr + off + 32 * 512);
            a3 = *(const float4*)(aptr + off + 32 * 512 + 4);
            b0 = *(const int4*)(bptr + off);
            b1 = *(const int4*)(bptr + off + 32 * 512);
            if (dual) {
                g0 = *(const int4*)(gptr + off);
                g1 = *(const int4*)(gptr + off + 32 * 512);
            }
        }
        if (dual) {
#pragma unroll
            for (int j = 0; j < 2; j++) {
                const int cu = j * 4 + fq;
                bf16x8 af = *(const bf16x8*)&As[buf][(cu * 64 + ((w * 16 + fm) ^ cu)) * 8];
#pragma unroll
                for (int nb = 0; nb < 4; nb++) {
                    bf16x8 bv = *(const bf16x8*)&Bs[buf][(cu * 64 + ((nb * 16 + fm) ^ cu)) * 8];
                    bf16x8 gv = *(const bf16x8*)&Bs2[buf][(cu * 64 + ((nb * 16 + fm) ^ cu)) * 8];
                    acc[nb]  = __builtin_amdgcn_mfma_f32_16x16x32_bf16(af, bv, acc[nb], 0, 0, 0);
                    acc2[nb] = __builtin_amdgcn_mfma_f32_16x16x32_bf16(af, gv, acc2[nb], 0, 0, 0);
                }
            }
        } else {
#pragma unroll
            for (int j = 0; j < 2; j++) {
                const int cu = j * 4 + fq;
                bf16x8 af = *(const bf16x8*)&As[buf][(cu * 64 + ((w * 16 + fm) ^ cu)) * 8];
#pragma unroll
                for (int nb = 0; nb < 4; nb++) {
                    bf16x8 bv = *(const bf16x8*)&Bs[buf][(cu * 64 + ((nb * 16 + fm) ^ cu)) * 8];
                    acc[nb] = __builtin_amdgcn_mfma_f32_16x16x32_bf16(af, bv, acc[nb], 0, 0, 0);
                }
            }
        }
        if (kti < 7) {
            const int nb_ = buf ^ 1;
            *(int4*)&As[nb_][la0] = pack8(a0, a1);
            *(int4*)&As[nb_][la1] = pack8(a2, a3);
            *(int4*)&Bs[nb_][la0] = b0; *(int4*)&Bs[nb_][la1] = b1;
            if (dual) { *(int4*)&Bs2[nb_][la0] = g0; *(int4*)&Bs2[nb_][la1] = g1; }
            __syncthreads();
        }
    }

#pragma unroll
    for (int nb = 0; nb < 4; nb++) {
        const int col = n0 + nb * 16 + fm;
        const float bb = dual ? bg[col] : 0.f;
#pragma unroll
        for (int r = 0; r < 4; r++) {
            const int row = row0 + w * 16 + fq * 4 + r;
            const float v = acc[nb][r];
            const ushort_t o = dual ? f2b(v * 2.f * sigm_f(acc2[nb][r] + bb))
                                    : f2b(phi_f(v));
            outp[(size_t)row * 512 + col] = o;
        }
    }
}

// ---------------------------------------------------------------------------
// Output projection: out[4096,512] fp32 = nb(bf16) @ Wo^T, double-buffered
// ---------------------------------------------------------------------------
__global__ __launch_bounds__(256) void outproj_k(const ushort_t* __restrict__ A,
                                                 const ushort_t* __restrict__ Bt,
                                                 float* __restrict__ out) {
    __shared__ __align__(16) unsigned short As[2][4096];
    __shared__ __align__(16) unsigned short Bs[2][4096];
    const int tid = threadIdx.x;
    const int row0 = blockIdx.x * 64, n0 = blockIdx.y * 64;
    const int w = tid >> 6, lane = tid & 63;
    const int cc = tid & 7, rr = tid >> 3;
    const int fm = lane & 15, fq = lane >> 4;
    const int la0 = (cc * 64 + (rr ^ cc)) * 8;
    const int la1 = (cc * 64 + ((rr + 32) ^ cc)) * 8;

    f32x4 acc[4];
#pragma unroll
    for (int i = 0; i < 4; i++) acc[i] = (f32x4){0.f, 0.f, 0.f, 0.f};

    const ushort_t* aptr = A  + (size_t)(row0 + rr) * 512 + cc * 8;
    const ushort_t* bptr = Bt + (size_t)(n0 + rr) * 512 + cc * 8;
    int4 ra0 = *(const int4*)(aptr);
    int4 ra1 = *(const int4*)(aptr + 32 * 512);
    int4 rb0 = *(const int4*)(bptr);
    int4 rb1 = *(const int4*)(bptr + 32 * 512);
    *(int4*)&As[0][la0] = ra0; *(int4*)&As[0][la1] = ra1;
    *(int4*)&Bs[0][la0] = rb0; *(int4*)&Bs[0][la1] = rb1;
    __syncthreads();

    for (int kti = 0; kti < 8; kti++) {
        const int buf = kti & 1;
        if (kti < 7) {
            const int off = (kti + 1) * 64;
            ra0 = *(const int4*)(aptr + off);
            ra1 = *(const int4*)(aptr + off + 32 * 512);
            rb0 = *(const int4*)(bptr + off);
            rb1 = *(const int4*)(bptr + off + 32 * 512);
        }
#pragma unroll
        for (int j = 0; j < 2; j++) {
            const int cu = j * 4 + fq;
            bf16x8 af = *(const bf16x8*)&As[buf][(cu * 64 + ((w * 16 + fm) ^ cu)) * 8];
#pragma unroll
            for (int nb = 0; nb < 4; nb++) {
                bf16x8 bv = *(const bf16x8*)&Bs[buf][(cu * 64 + ((nb * 16 + fm) ^ cu)) * 8];
                acc[nb] = __builtin_amdgcn_mfma_f32_16x16x32_bf16(af, bv, acc[nb], 0, 0, 0);
            }
        }
        if (kti < 7) {
            const int nb_ = buf ^ 1;
            *(int4*)&As[nb_][la0] = ra0; *(int4*)&As[nb_][la1] = ra1;
            *(int4*)&Bs[nb_][la0] = rb0; *(int4*)&Bs[nb_][la1] = rb1;
            __syncthreads();
        }
    }
#pragma unroll
    for (int nb = 0; nb < 4; nb++) {
        const int col = n0 + nb * 16 + fm;
#pragma unroll
        for (int r = 0; r < 4; r++) {
            const int row = row0 + w * 16 + fq * 4 + r;
            __builtin_nontemporal_store(acc[nb][r], &out[(size_t)row * 512 + col]);
        }
    }
}

// ---------------------------------------------------------------------------
// K2a: per-(b,h,chunk) RAW sums: kv[k][v] = sum_t kf[t][k]*vg[t][v]; ksum[k]
// ---------------------------------------------------------------------------
__global__ __launch_bounds__(256) void chunksum_k(const ushort_t* __restrict__ kb,
                                                  const ushort_t* __restrict__ vb,
                                                  float* __restrict__ kv,
                                                  float* __restrict__ ksum) {
    __shared__ __align__(16) float kf_c[64][68];
    __shared__ __align__(16) float vg_c[64][68];
    const int tid = threadIdx.x;
    const int bh = blockIdx.x, c = blockIdx.y;
    const int b = bh >> 3, h = bh & 7;
    const int r = tid >> 2, qq = tid & 3;
    {
        const size_t rowbase = ((size_t)(b * TDIM + c * 64 + r)) * 512 + h * 64 + qq * 16;
        bfu k0, k1, v0, v1;
        k0.i4 = *(const int4*)(kb + rowbase);
        k1.i4 = *(const int4*)(kb + rowbase + 8);
        v0.i4 = *(const int4*)(vb + rowbase);
        v1.i4 = *(const int4*)(vb + rowbase + 8);
#pragma unroll
        for (int j = 0; j < 8; j++) {
            kf_c[r][qq * 16 + j]     = b2f(k0.us[j]);
            kf_c[r][qq * 16 + 8 + j] = b2f(k1.us[j]);
            vg_c[r][qq * 16 + j]     = b2f(v0.us[j]);
            vg_c[r][qq * 16 + 8 + j] = b2f(v1.us[j]);
        }
    }
    __syncthreads();
    const int k0i = (tid >> 4) * 4;
    const int v0i = (tid & 15) * 4;
    float4 a4[4];
#pragma unroll
    for (int i = 0; i < 4; i++) a4[i] = make_float4(0.f, 0.f, 0.f, 0.f);
    for (int t = 0; t < 64; t++) {
        float4 kk4 = *(const float4*)&kf_c[t][k0i];
        float4 vv  = *(const float4*)&vg_c[t][v0i];
        FMA4(a4[0], kk4.x, vv); FMA4(a4[1], kk4.y, vv);
        FMA4(a4[2], kk4.z, vv); FMA4(a4[3], kk4.w, vv);
    }
    const size_t base = (size_t)(bh * 16 + c) * 64;
#pragma unroll
    for (int i = 0; i < 4; i++)
        *(float4*)(kv + (base + k0i + i) * 64 + v0i) = a4[i];
    if (tid < 64) {
        float s = 0.f;
        for (int t = 0; t < 64; t++) s += kf_c[t][tid];
        ksum[base + tid] = s;
    }
}

// ---------------------------------------------------------------------------
// FUSED: per-(bh, diag): prefix(kv,ksum) + diag S + denom + numer + full
// att_map tile-row (streamed, double-buffered, NT stores) + zero-fill.
// grid (32, 16), diag = 15 - blockIdx.y (heavy blocks first)
// dynamic LDS = 70144 bytes
// ---------------------------------------------------------------------------
__global__ __launch_bounds__(256) void fused_k(const ushort_t* __restrict__ qb,
                                               const ushort_t* __restrict__ kb,
                                               const ushort_t* __restrict__ vb,
                                               const float* __restrict__ kvc,
                                               const float* __restrict__ ksum,
                                               ushort_t* __restrict__ nbo,
                                               float* __restrict__ att) {
    extern __shared__ __align__(16) char smem[];
    unsigned short* qs   = (unsigned short*)smem;            // 4096 elem
    unsigned short* ksb  = qs + 4096;                        // 2 x 4096
    unsigned short* vrow = ksb + 8192;                       // 64x72
    float* kvf  = (float*)(vrow + 64 * 72);                  // 64x68
    float* sc   = kvf + 64 * 68;                             // 64x68
    float* kpre = sc + 64 * 68;                              // 64
    float* ps   = kpre + 64;                                 // 64x4
    float* inv_s = ps + 256;                                 // 64

    const int tid = threadIdx.x;
    const int bh = blockIdx.x, diag = 15 - (int)blockIdx.y;
    const int tt0 = diag * 64;
    const int b = bh >> 3, h = bh & 7;
    const int w = tid >> 6, lane = tid & 63;
    const int fm = lane & 15, fq = lane >> 4;
    const int rr = tid >> 3, cc = tid & 7;
    const int la0 = (cc * 64 + (rr ^ cc)) * 8;
    const int la1 = (cc * 64 + ((rr + 32) ^ cc)) * 8;

    const ushort_t* kbase = kb + ((size_t)(b * TDIM + rr)) * 512 + h * 64 + cc * 8;

    // ---- P0: staging ----
    {
        const ushort_t* qptr = qb + ((size_t)(b * TDIM + tt0 + rr)) * 512 + h * 64 + cc * 8;
        *(int4*)&qs[la0] = *(const int4*)qptr;
        *(int4*)&qs[la1] = *(const int4*)(qptr + 32 * 512);
        const ushort_t* kptr = kbase + (size_t)tt0 * 512;
        *(int4*)&ksb[la0] = *(const int4*)kptr;
        *(int4*)&ksb[la1] = *(const int4*)(kptr + 32 * 512);
        // V rows coalesced
        const int r = tid >> 2, qq = tid & 3;
        const ushort_t* vptr = vb + ((size_t)(b * TDIM + tt0 + r)) * 512 + h * 64 + qq * 16;
        *(int4*)&vrow[r * 72 + qq * 16]     = *(const int4*)vptr;
        *(int4*)&vrow[r * 72 + qq * 16 + 8] = *(const int4*)(vptr + 8);
        // KVpre accumulate over raw chunk sums
        float4 a4[4];
#pragma unroll
        for (int u = 0; u < 4; u++) a4[u] = make_float4(0.f, 0.f, 0.f, 0.f);
        for (int c2 = 0; c2 < diag; c2++) {
            const float* p = kvc + (size_t)(bh * 16 + c2) * 4096 + r * 64 + qq * 16;
#pragma unroll
            for (int u = 0; u < 4; u++) {
                float4 x = *(const float4*)(p + 4 * u);
                a4[u].x += x.x; a4[u].y += x.y; a4[u].z += x.z; a4[u].w += x.w;
            }
        }
#pragma unroll
        for (int u = 0; u < 4; u++) *(float4*)&kvf[r * 68 + qq * 16 + 4 * u] = a4[u];
        if (tid < 64) {
            float s = 0.f;
            for (int c2 = 0; c2 < diag; c2++)
                s += ksum[(size_t)(bh * 16 + c2) * 64 + tid];
            kpre[tid] = s;
        }
    }
    __syncthreads();

    // ---- P1: diag S = Q.K^T (keep sa in regs); prefetch att chunk 0 ----
    f32x4 sa[4];
    {
        int4 rk0 = {0,0,0,0}, rk1 = {0,0,0,0};
        if (diag > 0) {
            rk0 = *(const int4*)(kbase);
            rk1 = *(const int4*)(kbase + 32 * 512);
        }
#pragma unroll
        for (int i = 0; i < 4; i++) sa[i] = (f32x4){0.f, 0.f, 0.f, 0.f};
#pragma unroll
        for (int j = 0; j < 2; j++) {
            const int cu = j * 4 + fq;
            bf16x8 aqf = *(const bf16x8*)&qs[(cu * 64 + ((w * 16 + fm) ^ cu)) * 8];
#pragma unroll
            for (int nb = 0; nb < 4; nb++) {
                bf16x8 bk = *(const bf16x8*)&ksb[(cu * 64 + ((nb * 16 + fm) ^ cu)) * 8];
                sa[nb] = __builtin_amdgcn_mfma_f32_16x16x32_bf16(aqf, bk, sa[nb], 0, 0, 0);
            }
        }
#pragma unroll
        for (int nb = 0; nb < 4; nb++) {
            const int s_l = nb * 16 + fm;
#pragma unroll
            for (int r = 0; r < 4; r++) {
                const int t_l = w * 16 + fq * 4 + r;
                sc[t_l * 68 + s_l] = (s_l <= t_l) ? sa[nb][r] : 0.f;
            }
        }
        if (diag > 0) {
            *(int4*)&ksb[4096 + la0] = rk0;
            *(int4*)&ksb[4096 + la1] = rk1;
        }
    }
    __syncthreads();

    // ---- P2: denom -> inv_s ----
    {
        const int rw = tid >> 2, sq = tid & 3;
        float p = 0.f;
#pragma unroll
        for (int s = sq * 16; s < sq * 16 + 16; s++) p += sc[rw * 68 + s];
#pragma unroll
        for (int kd = sq * 16; kd < sq * 16 + 16; kd++) {
            const int cu = kd >> 3;
            p += b2f(qs[(cu * 64 + (rw ^ cu)) * 8 + (kd & 7)]) * kpre[kd];
        }
        ps[rw * 4 + sq] = p;
    }
    __syncthreads();
    {
        const int rw = tid >> 2, sq = tid & 3;
        if (sq == 0) {
            float den = ps[rw * 4] + ps[rw * 4 + 1] + ps[rw * 4 + 2] + ps[rw * 4 + 3];
            inv_s[rw] = 1.f / (den + EPSF);
        }
    }
    __syncthreads();

    // ---- P3: numer = Q.KVpre^T + P.V^T, scaled; write nbo bf16 ----
    {
        f32x4 oa[4];
#pragma unroll
        for (int i = 0; i < 4; i++) oa[i] = (f32x4){0.f, 0.f, 0.f, 0.f};
        bf16x8 aqv[2], apv[2];
#pragma unroll
        for (int j = 0; j < 2; j++) {
            const int cu = j * 4 + fq;
            aqv[j] = *(const bf16x8*)&qs[(cu * 64 + ((w * 16 + fm) ^ cu)) * 8];
            bfu t;
#pragma unroll
            for (int e2 = 0; e2 < 8; e2++) t.us[e2] = f2b(sc[(w * 16 + fm) * 68 + cu * 8 + e2]);
            apv[j] = t.v;
        }
#pragma unroll
        for (int nb = 0; nb < 4; nb++) {
            const int v = nb * 16 + fm;
#pragma unroll
            for (int j = 0; j < 2; j++) {
                const int cu = j * 4 + fq;
                bfu tkv, tv;
#pragma unroll
                for (int e = 0; e < 8; e++) {
                    tkv.us[e] = f2b(kvf[(cu * 8 + e) * 68 + v]);
                    tv.us[e]  = vrow[(cu * 8 + e) * 72 + v];
                }
                oa[nb] = __builtin_amdgcn_mfma_f32_16x16x32_bf16(aqv[j], tkv.v, oa[nb], 0, 0, 0);
                oa[nb] = __builtin_amdgcn_mfma_f32_16x16x32_bf16(apv[j], tv.v, oa[nb], 0, 0, 0);
            }
        }
#pragma unroll
        for (int nb = 0; nb < 4; nb++) {
            const int vcol = nb * 16 + fm;
#pragma unroll
            for (int r = 0; r < 4; r++) {
                const int t_l = w * 16 + fq * 4 + r;
                const float val = oa[nb][r] * inv_s[t_l];
                nbo[((size_t)(b * TDIM + tt0 + t_l)) * 512 + h * 64 + vcol] = f2b(val);
            }
        }
    }

    // ---- P4: att_map row of tiles ----
    bf16x8 aq[2];
    float invr[4];
#pragma unroll
    for (int j = 0; j < 2; j++) {
        const int cu = j * 4 + fq;
        aq[j] = *(const bf16x8*)&qs[(cu * 64 + ((w * 16 + fm) ^ cu)) * 8];
    }
#pragma unroll
    for (int r = 0; r < 4; r++) invr[r] = inv_s[w * 16 + fq * 4 + r];

    float* attb = att + (size_t)bh * TDIM * TDIM;
    int4 rk0, rk1;
    for (int st = 0; st < diag; st++) {
        const int bsel = (st + 1) & 1;  // st=0 -> ksb[1]
        if (st + 1 < diag) {
            const size_t off = (size_t)(st + 1) * 64 * 512;
            rk0 = *(const int4*)(kbase + off);
            rk1 = *(const int4*)(kbase + off + 32 * 512);
        }
        f32x4 pa[4];
#pragma unroll
        for (int i = 0; i < 4; i++) pa[i] = (f32x4){0.f, 0.f, 0.f, 0.f};
#pragma unroll
        for (int j = 0; j < 2; j++) {
            const int cu = j * 4 + fq;
#pragma unroll
            for (int nb = 0; nb < 4; nb++) {
                bf16x8 bk = *(const bf16x8*)&ksb[bsel * 4096 +
                                                 (cu * 64 + ((nb * 16 + fm) ^ cu)) * 8];
                pa[nb] = __builtin_amdgcn_mfma_f32_16x16x32_bf16(aq[j], bk, pa[nb], 0, 0, 0);
            }
        }
        const int s0 = st * 64;
#pragma unroll
        for (int nb = 0; nb < 4; nb++) {
            const int s_g = s0 + nb * 16 + fm;
#pragma unroll
            for (int r = 0; r < 4; r++) {
                const int t_g = tt0 + w * 16 + fq * 4 + r;
                __builtin_nontemporal_store(pa[nb][r] * invr[r],
                                            &attb[(size_t)t_g * TDIM + s_g]);
            }
        }
        if (st + 1 < diag) {
            *(int4*)&ksb[(bsel ^ 1) * 4096 + la0] = rk0;
            *(int4*)&ksb[(bsel ^ 1) * 4096 + la1] = rk1;
            __syncthreads();
        }
    }
    // diagonal tile from sa (regs)
#pragma unroll
    for (int nb = 0; nb < 4; nb++) {
        const int s_l = nb * 16 + fm;
#pragma unroll
        for (int r = 0; r < 4; r++) {
            const int t_l = w * 16 + fq * 4 + r;
            const float val = (s_l <= t_l) ? sa[nb][r] * invr[r] : 0.f;
            __builtin_nontemporal_store(val,
                &attb[(size_t)(tt0 + t_l) * TDIM + tt0 + s_l]);
        }
    }
    // zero-fill right of diagonal
    {
        const f32x4 z = (f32x4){0.f, 0.f, 0.f, 0.f};
        const int r = tid >> 2, qq = tid & 3;
        float* rowp = attb + (size_t)(tt0 + r) * TDIM;
        for (int c0 = (diag + 1) * 64 + qq * 4; c0 < TDIM; c0 += 16)
            __builtin_nontemporal_store(z, (f32x4*)(rowp + c0));
    }
}

// ---------------------------------------------------------------------------
extern "C" void kernel_launch(void* const* d_in, const int* in_sizes, int n_in,
                              void* d_out, int out_size, void* d_ws, size_t ws_size,
                              hipStream_t stream) {
    (void)in_sizes; (void)n_in; (void)out_size; (void)ws_size;
    const float* query = (const float*)d_in[0];
    const float* key   = (const float*)d_in[1];
    const float* value = (const float*)d_in[2];
    const float* Wq    = (const float*)d_in[3];
    const float* Wk    = (const float*)d_in[4];
    const float* Wv    = (const float*)d_in[5];
    const float* Wg    = (const float*)d_in[6];
    const float* bg    = (const float*)d_in[7];
    const float* Wo    = (const float*)d_in[8];
    float* out = (float*)d_out;                  // [B,T,M]
    float* att = (float*)d_out + 2097152;        // [B,H,T,T]
    float* ws  = (float*)d_ws;
    float* ksum = ws + OFF_KSUM;
    float* kv   = ws + OFF_KV;
    ushort_t* ub  = (ushort_t*)((char*)d_ws + FLOAT_BYTES);
    ushort_t* qp  = ub + UOFF_QP;
    ushort_t* kp  = ub + UOFF_KP;
    ushort_t* vp  = ub + UOFF_VP;
    ushort_t* nbp = ub + UOFF_NB;
    ushort_t* wqt = ub + UOFF_WQ;
    ushort_t* wkt = ub + UOFF_WK;
    ushort_t* wvt = ub + UOFF_WV;
    ushort_t* wgt = ub + UOFF_WG;
    ushort_t* wot = ub + UOFF_WO;

    dim3 blk(256);
    castwt_all<<<dim3(16, 16, 5), blk, 0, stream>>>(Wq, Wk, Wv, Wg, Wo,
                                                    wqt, wkt, wvt, wgt, wot);
    proj_k<<<dim3(64, 8, 3), blk, 0, stream>>>(query, key, value,
                                               wqt, wkt, wvt, wgt, bg, qp, kp, vp);
    chunksum_k<<<dim3(32, 16), blk, 0, stream>>>(kp, vp, kv, ksum);
    fused_k<<<dim3(32, 16), blk, 70144, stream>>>(qp, kp, vp, kv, ksum, nbp, att);
    outproj_k<<<dim3(64, 8), blk, 0, stream>>>(nbp, wot, out);
}